// Round 8
// baseline (416.016 us; speedup 1.0000x reference)
//
#include <hip/hip_runtime.h>
#include <cstddef>

// DynamicNetwork via split-bf16 MFMA (hi/lo, 3 MFMA per product).
// R8: algebraic fusion — nodes 2..5 never materialized.
// R15: P1 = node1@Ps computed once; h-GEMMs K 816->400 (K-sum 1824).
// R16: GEMM de-staged. Six rounds showed ~1us/K-step regardless of schedule —
//   the LDS+barrier structure itself (vmcnt(0) drain per __syncthreads) was the
//   floor. All GEMM operands are L2-resident per XCD (B 0.8MB shared, A 1.7MB
//   XCD-local, P1 1.6MB), so fragments are now read DIRECTLY from global:
//   no LDS, no barriers, waves independent. Kernel templated on NK -> full
//   unroll, load offsets fold to imm (max 800B), compiler pipelines with
//   counted vmcnt across iterations (nothing drains them).

typedef short short8 __attribute__((ext_vector_type(8)));
typedef float floatx16 __attribute__((ext_vector_type(16)));

#define EMB_BLOCKS 832
#define SN0 224   // node0 k-stride (208 used)
#define SN1 448   // node1 k-stride (416 used)
#define SH  416   // hidden k-stride (400 used)

__device__ __forceinline__ unsigned short f2bf(float f) {
    unsigned int u = __float_as_uint(f);
    u += 0x7fffu + ((u >> 16) & 1u);
    return (unsigned short)(u >> 16);
}
__device__ __forceinline__ float bf2f(unsigned short h) {
    return __uint_as_float((unsigned int)h << 16);
}
__device__ __forceinline__ void split2(float v, unsigned short& h, unsigned short& l) {
    h = f2bf(v);
    l = f2bf(v - bf2f(h));
}

// ---------------- prep1: column sums (39 blocks) + alpha scalars ----------------
__global__ __launch_bounds__(256) void prep1_kernel(
    const float* __restrict__ Pd, const float* __restrict__ Ps, const float* __restrict__ Pb,
    const float* __restrict__ a0, const float* __restrict__ a1,
    const float* __restrict__ a2, const float* __restrict__ a3,
    float* __restrict__ scal,
    float* __restrict__ csd, float* __restrict__ css, float* __restrict__ csb)
{
    int t = threadIdx.x;
    int y = blockIdx.y;
    int c = t & 31, rg = t >> 5;
    int col = blockIdx.x * 32 + c;
    const float* src = (y==0) ? Pd : (y==1) ? Ps : Pb;
    int K = (y==0) ? 208 : (y==1) ? 416 : 400;
    float* out = (y==0) ? csd : (y==1) ? css : csb;
    float s = 0.f;
    if (col < 400)
        for (int k = rg; k < K; k += 8) s += src[(size_t)k*400 + col];
    __shared__ float red[8][32];
    red[rg][c] = s;
    __syncthreads();
    if (rg == 0 && col < 400) {
        float tot = 0.f;
        #pragma unroll
        for (int r = 0; r < 8; ++r) tot += red[r][c];
        out[col] = tot;
    }
    if (blockIdx.x == 0 && y == 0 && t < 4) {
        int i = t;
        const float* a = (i==0) ? a0 : (i==1) ? a1 : (i==2) ? a2 : a3;
        int np = 2 + i;
        float sum1 = 0.f, sum2 = 0.f, sumc = 0.f;
        for (int j = 0; j < np; ++j) { sum1 += a[j]; sum2 += a[np+j]; }
        for (int j = 0; j < 4; ++j) sumc += a[2*np+j];
        int i1 = (i==0) ? 0 : 1;
        int i2 = i + 1;
        int kk = i;
        float s1 = a[i1],      c1 = sum1 - s1;
        float s2 = a[np+i2],   c2 = sum2 - s2;
        float sk = a[2*np+kk], ck = sumc - sk;
        float* sl = scal + i*8;
        if (i == 0) { sl[0]=s1; sl[1]=c1; sl[2]=s2; sl[3]=c2; }
        else        { sl[0]=s2; sl[1]=c2; sl[2]=s1; sl[3]=c1; }
        sl[4] = sk; sl[5] = ck;
    }
}

// ---------------- prep2: w0 = s1*Pd (K=208) ; ws = Ps unscaled (K=416) ----------------
__global__ __launch_bounds__(256) void prep2_kernel(
    const float* __restrict__ Pd, const float* __restrict__ Ps,
    const float* __restrict__ scal,
    unsigned short* __restrict__ w0, unsigned short* __restrict__ ws)
{
    int z = blockIdx.z;
    int Kp = (z==0) ? 208 : 416;
    int Kw = Kp;
    const float* src = (z==0) ? Pd : Ps;
    unsigned short* dst = (z==0) ? w0 : ws;

    int ktiles = (Kp + 63) >> 6;
    if ((int)blockIdx.y >= ktiles) return;
    float sc = (z==0) ? scal[0] : 1.f;
    int k0 = blockIdx.y * 64, n0 = blockIdx.x * 64;
    __shared__ float T[64][65];
    int t = threadIdx.x;
    {
        int kr = t >> 2, c0 = (t & 3) * 16;
        int gk = k0 + kr;
        bool kok = gk < Kp;
        for (int j = 0; j < 16; j += 4) {
            int n = n0 + c0 + j;
            float4 v = make_float4(0.f,0.f,0.f,0.f);
            if (kok && n < 400) v = *(const float4*)&src[(size_t)gk*400 + n];
            T[kr][c0+j+0] = v.x * sc;
            T[kr][c0+j+1] = v.y * sc;
            T[kr][c0+j+2] = v.z * sc;
            T[kr][c0+j+3] = v.w * sc;
        }
    }
    __syncthreads();
    {
        int nr = t >> 2, kc0 = (t & 3) * 16;
        int gn = n0 + nr;
        int gk0 = k0 + kc0;
        if (gk0 >= Kp) return;
        unsigned short hb[16], lb[16];
        for (int j = 0; j < 16; ++j) {
            float v = (gn < 400) ? T[kc0+j][nr] : 0.f;
            split2(v, hb[j], lb[j]);
        }
        unsigned short* dh = dst + (size_t)gn*Kw + gk0;
        unsigned short* dl = dst + (size_t)512*Kw + (size_t)gn*Kw + gk0;
        *(uint4*)&dh[0] = *(uint4*)&hb[0]; *(uint4*)&dh[8] = *(uint4*)&hb[8];
        *(uint4*)&dl[0] = *(uint4*)&lb[0]; *(uint4*)&dl[8] = *(uint4*)&lb[8];
    }
}

// ---------------- prepM: M_g = s2_g * sk_{g-1} * (Wc_{g-1} @ Pb), g = z+1 ----------------
__global__ __launch_bounds__(256) void prepM_kernel(
    const float* __restrict__ Wc, const float* __restrict__ Pb,
    const float* __restrict__ scal,
    unsigned short* __restrict__ w1, unsigned short* __restrict__ w2,
    unsigned short* __restrict__ w3)
{
    int z = blockIdx.z;                   // 0..2 -> GEMM g = z+1
    unsigned short* dst = (z==0) ? w1 : (z==1) ? w2 : w3;
    const float* A = Wc + (size_t)z*5*160000;   // Wc[z, kk=z] : [400k][400j]
    float scale = scal[(z+1)*8+0] * scal[z*8+4];
    const int Kw = 400;

    __shared__ float As[16][68];   // [j][k]
    __shared__ float Ws[16][68];   // [j][n]
    int t = threadIdx.x;
    int tx = t & 15, ty = t >> 4;
    int bk = blockIdx.y * 64;
    int bn = blockIdx.x * 64;
    int arow = t >> 2;
    int aj4  = (t & 3) << 2;
    int wrow = t >> 4;
    int wc4  = (t & 15) << 2;
    float acc[4][4] = {};
    for (int j0 = 0; j0 < 400; j0 += 16) {
        float4 av = make_float4(0.f,0.f,0.f,0.f);
        if (bk + arow < 400) av = *(const float4*)&A[(size_t)(bk+arow)*400 + j0 + aj4];
        float4 wv = make_float4(0.f,0.f,0.f,0.f);
        if (bn + wc4 < 400) wv = *(const float4*)&Pb[(size_t)(j0+wrow)*400 + bn + wc4];
        __syncthreads();
        As[aj4+0][arow] = av.x;
        As[aj4+1][arow] = av.y;
        As[aj4+2][arow] = av.z;
        As[aj4+3][arow] = av.w;
        *(float4*)&Ws[wrow][wc4] = wv;
        __syncthreads();
        #pragma unroll
        for (int jj = 0; jj < 16; ++jj) {
            float4 a4 = *(const float4*)&As[jj][ty<<2];
            float4 b4 = *(const float4*)&Ws[jj][tx<<2];
            acc[0][0] += a4.x*b4.x; acc[0][1] += a4.x*b4.y; acc[0][2] += a4.x*b4.z; acc[0][3] += a4.x*b4.w;
            acc[1][0] += a4.y*b4.x; acc[1][1] += a4.y*b4.y; acc[1][2] += a4.y*b4.z; acc[1][3] += a4.y*b4.w;
            acc[2][0] += a4.z*b4.x; acc[2][1] += a4.z*b4.y; acc[2][2] += a4.z*b4.z; acc[2][3] += a4.z*b4.w;
            acc[3][0] += a4.w*b4.x; acc[3][1] += a4.w*b4.y; acc[3][2] += a4.w*b4.z; acc[3][3] += a4.w*b4.w;
        }
    }
    int gk0 = bk + (ty << 2);
    int gn0 = bn + (tx << 2);
    #pragma unroll
    for (int ik = 0; ik < 4; ++ik) {
        int gk = gk0 + ik;
        if (gk >= 400) break;
        #pragma unroll
        for (int in = 0; in < 4; ++in) {
            int gn = gn0 + in;
            float v = (gn < 400) ? acc[ik][in] * scale : 0.f;
            unsigned short h16, l16; split2(v, h16, l16);
            dst[(size_t)gn*Kw + gk] = h16;
            dst[(size_t)512*Kw + (size_t)gn*Kw + gk] = l16;
        }
    }
}

// ---------------- prepvec: C_i, gv_i, scalar consts (56 blocks) ----------------
__global__ __launch_bounds__(256) void prepvec_kernel(
    const float* __restrict__ scal,
    const float* __restrict__ csd, const float* __restrict__ css, const float* __restrict__ csb,
    const float* __restrict__ Wc, const float* __restrict__ bc,
    const float* __restrict__ clf_w, const float* __restrict__ Pb,
    float* __restrict__ cv, float* __restrict__ gv, float* __restrict__ scl2)
{
    int i = blockIdx.y;
    int tid = threadIdx.x;
    int tbase = blockIdx.x * 32;
    const float* cw = clf_w + i*400;
    float ski = scal[i*8+4], cki = scal[i*8+5];
    const float* A = Wc + (size_t)i*5*160000;

    int wv = tid >> 6, lane = tid & 63;
    #pragma unroll
    for (int q = 0; q < 8; ++q) {
        int t = tbase + wv*8 + q;
        float s = 0.f;
        if (t < 400) {
            const float* wr = A + (size_t)t*400;
            for (int j = lane; j < 400; j += 64) s += wr[j]*cw[j];
            #pragma unroll
            for (int o = 32; o > 0; o >>= 1) s += __shfl_xor(s, o);
        }
        if (lane == 0) gv[i*448 + t] = (t < 400) ? ski * s : 0.f;
    }

    __shared__ float bpred[8][32];
    int t = tbase + (tid & 31);
    int jc = tid >> 5;
    float bp_part = 0.f;
    if (i > 0 && t < 400) {
        const float* bcp = bc + (size_t)(i-1)*5*400;
        for (int j = jc*50; j < jc*50 + 50; ++j)
            bp_part += bcp[j] * Pb[(size_t)j*400 + t];
    }
    bpred[jc][tid & 31] = bp_part;
    __syncthreads();
    if (tid < 32) {
        float bp = 0.f;
        #pragma unroll
        for (int r = 0; r < 8; ++r) bp += bpred[r][tid];
        float c = 0.f;
        if (t < 400) {
            if (i == 0) {
                c = scal[1]*csd[t] + scal[3]*css[t];
            } else {
                float s2 = scal[i*8+0], c2 = scal[i*8+1];
                float c1 = scal[i*8+3];
                float skp = scal[(i-1)*8+4], ckp = scal[(i-1)*8+5];
                c = c1*css[t] + (c2 + s2*ckp)*csb[t] + s2*skp*bp;
            }
        }
        cv[i*448 + t] = c;
    }

    if (blockIdx.x == 0) {
        const float* bci = bc + (size_t)i*5*400;
        float sc = 0.f;
        for (int j = tid; j < 400; j += 256) sc += (ski*bci[j] + cki)*cw[j];
        #pragma unroll
        for (int o = 32; o > 0; o >>= 1) sc += __shfl_down(sc, o);
        __shared__ float red[4];
        int wv2 = tid >> 6, ln = tid & 63;
        if (ln == 0) red[wv2] = sc;
        __syncthreads();
        if (tid == 0) scl2[i] = red[0]+red[1]+red[2]+red[3];
    }
}

// ---------------- embed: node0/node1 bf16 hi/lo planes (padded strides) ----------------
__global__ __launch_bounds__(256) void embed_kernel(
    const float* __restrict__ rd, const int* __restrict__ rs,
    const float* __restrict__ emb,
    unsigned short* __restrict__ n0h, unsigned short* __restrict__ n0l,
    unsigned short* __restrict__ n1h, unsigned short* __restrict__ n1l,
    float* __restrict__ partial)
{
    int tid0 = blockIdx.x*256 + threadIdx.x;
    int nth = gridDim.x*256;
    float ssq = 0.f, dsq = 0.f;
    for (int it = tid0; it < 8192*26; it += nth) {
        int b = it / 26, s = it - b*26;
        int row = 13 + 50000*s + rs[b*26 + s];
        const float* e = emb + (size_t)row*16;
        float4 e0 = *(const float4*)&e[0], e1 = *(const float4*)&e[4];
        float4 e2 = *(const float4*)&e[8], e3 = *(const float4*)&e[12];
        float vv[16] = {e0.x,e0.y,e0.z,e0.w, e1.x,e1.y,e1.z,e1.w,
                        e2.x,e2.y,e2.z,e2.w, e3.x,e3.y,e3.z,e3.w};
        unsigned short hb[16], lb[16];
        for (int j = 0; j < 16; ++j) { ssq += vv[j]*vv[j]; split2(vv[j], hb[j], lb[j]); }
        size_t off = (size_t)b*SN1 + s*16;
        *(uint4*)&n1h[off] = *(uint4*)&hb[0]; *(uint4*)&n1h[off+8] = *(uint4*)&hb[8];
        *(uint4*)&n1l[off] = *(uint4*)&lb[0]; *(uint4*)&n1l[off+8] = *(uint4*)&lb[8];
    }
    for (int it = tid0; it < 8192*13; it += nth) {
        int b = it / 13, f = it - b*13;
        float sc = rd[b*13 + f];
        const float* e = emb + (size_t)f*16;
        float4 e0 = *(const float4*)&e[0], e1 = *(const float4*)&e[4];
        float4 e2 = *(const float4*)&e[8], e3 = *(const float4*)&e[12];
        float vv[16] = {e0.x,e0.y,e0.z,e0.w, e1.x,e1.y,e1.z,e1.w,
                        e2.x,e2.y,e2.z,e2.w, e3.x,e3.y,e3.z,e3.w};
        unsigned short hb[16], lb[16];
        for (int j = 0; j < 16; ++j) { float v = vv[j]*sc; dsq += v*v; split2(v, hb[j], lb[j]); }
        size_t off = (size_t)b*SN0 + f*16;
        *(uint4*)&n0h[off] = *(uint4*)&hb[0]; *(uint4*)&n0h[off+8] = *(uint4*)&hb[8];
        *(uint4*)&n0l[off] = *(uint4*)&lb[0]; *(uint4*)&n0l[off+8] = *(uint4*)&lb[8];
    }
    for (int o = 32; o > 0; o >>= 1) { ssq += __shfl_down(ssq, o); dsq += __shfl_down(dsq, o); }
    __shared__ float red[8];
    int wave = threadIdx.x >> 6, lane = threadIdx.x & 63;
    if (lane == 0) { red[wave] = dsq; red[4+wave] = ssq; }
    __syncthreads();
    if (threadIdx.x == 0) {
        partial[blockIdx.x*2]   = red[0]+red[1]+red[2]+red[3];
        partial[blockIdx.x*2+1] = red[4]+red[5]+red[6]+red[7];
    }
}

// blocks 0..31: out[b] = clf_b + sum_i scl2[i]; block 32: regs
__global__ __launch_bounds__(256) void finalize_kernel(
    const float* __restrict__ clf_b, const float* __restrict__ partial,
    const float* __restrict__ scl2, float* __restrict__ out)
{
    if (blockIdx.x < 32) {
        float base = clf_b[0] + scl2[0] + scl2[1] + scl2[2] + scl2[3];
        out[blockIdx.x*256 + threadIdx.x] = base;
        return;
    }
    float d = 0.f, s = 0.f;
    for (int i = threadIdx.x; i < EMB_BLOCKS; i += 256) { d += partial[2*i]; s += partial[2*i+1]; }
    for (int o = 32; o > 0; o >>= 1) { d += __shfl_down(d, o); s += __shfl_down(s, o); }
    __shared__ float red[8];
    int wave = threadIdx.x >> 6, lane = threadIdx.x & 63;
    if (lane == 0) { red[wave] = d; red[4+wave] = s; }
    __syncthreads();
    if (threadIdx.x == 0) {
        float dd = red[0]+red[1]+red[2]+red[3];
        float ss = red[4]+red[5]+red[6]+red[7];
        out[8192] = 1e-5f * (sqrtf(dd) + sqrtf(ss));
    }
}

// ---------------- R16 MFMA GEMM: direct-from-global fragments, no LDS, no barriers ----
// Grid 512 = 128 mt x 4 nt (XCD swizzle: each XCD reads a 1.7MB A slice + the
// shared 0.8MB B planes + 1.6MB P1 slice -> all L2-resident).
// 256 thr = 4 waves; wave (mw,nw) owns 32 rows x 64 cols over full K with 2 acc.
// Fragments are per-lane 16B row-gathers straight from global (identical values
// to the old LDS path). NK is a template constant -> full unroll, offsets fold
// to immediates, compiler pipelines loads with counted vmcnt (no drains).
template<int NK>
__global__ __launch_bounds__(256, 4) void mfma_gemm(
    const unsigned short* __restrict__ a1h, const unsigned short* __restrict__ a1l, int sA,
    const unsigned short* __restrict__ bph, int Kw,
    const float* __restrict__ vec,
    unsigned short* __restrict__ ch, unsigned short* __restrict__ cl,
    const float* __restrict__ lw, float* __restrict__ lout,
    float* __restrict__ p1out, const float* __restrict__ fadd, const float* __restrict__ fsp)
{
    int tid = threadIdx.x;
    int bid = blockIdx.x;
    int xcd = bid & 7, idx = bid >> 3;
    int mt = xcd*16 + (idx >> 2);
    int nt = idx & 3;
    int bm = mt * 64, bn = nt * 128;

    int W = tid >> 6, lane = tid & 63;
    int mw = W & 1, nw = W >> 1;
    int r31 = lane & 31, hh = lane >> 5;

    int arow = bm + mw*32 + r31;
    int brow = bn + nw*64 + r31;

    const unsigned short* Ah  = a1h + (size_t)arow*sA + hh*8;
    const unsigned short* Al  = a1l + (size_t)arow*sA + hh*8;
    const unsigned short* B0h = bph + (size_t)brow*Kw + hh*8;
    const unsigned short* B1h = B0h + (size_t)32*Kw;
    const unsigned short* B0l = B0h + (size_t)512*Kw;
    const unsigned short* B1l = B1h + (size_t)512*Kw;

    floatx16 acc0, acc1;
    for (int i = 0; i < 16; ++i) { acc0[i] = 0.f; acc1[i] = 0.f; }

    #pragma unroll
    for (int k = 0; k < NK; ++k) {
        short8 a_h = *(const short8*)(Ah  + k*16);
        short8 a_l = *(const short8*)(Al  + k*16);
        short8 b0h = *(const short8*)(B0h + k*16);
        short8 b1h = *(const short8*)(B1h + k*16);
        short8 b0l = *(const short8*)(B0l + k*16);
        short8 b1l = *(const short8*)(B1l + k*16);
        acc0 = __builtin_amdgcn_mfma_f32_32x32x16_bf16(a_h, b0h, acc0,0,0,0);
        acc1 = __builtin_amdgcn_mfma_f32_32x32x16_bf16(a_h, b1h, acc1,0,0,0);
        acc0 = __builtin_amdgcn_mfma_f32_32x32x16_bf16(a_h, b0l, acc0,0,0,0);
        acc1 = __builtin_amdgcn_mfma_f32_32x32x16_bf16(a_h, b1l, acc1,0,0,0);
        acc0 = __builtin_amdgcn_mfma_f32_32x32x16_bf16(a_l, b0h, acc0,0,0,0);
        acc1 = __builtin_amdgcn_mfma_f32_32x32x16_bf16(a_l, b1h, acc1,0,0,0);
    }

    // Epilogue: each wave owns its full-K 32x64 quadrant pair.
    int gn0 = bn + nw*64 + r31;
    int gn1 = gn0 + 32;
    bool ok0 = gn0 < 400, ok1 = gn1 < 400;

    if (p1out) {
        #pragma unroll
        for (int j = 0; j < 16; ++j) {
            int gm = bm + mw*32 + (j & 3) + 8*(j >> 2) + 4*hh;
            if (ok0) p1out[(size_t)gm*400 + gn0] = acc0[j];
            if (ok1) p1out[(size_t)gm*400 + gn1] = acc1[j];
        }
        return;
    }

    float vc0 = ok0 ? vec[gn0] : 0.f;
    float vc1 = ok1 ? vec[gn1] : 0.f;
    float wv0 = ok0 ? lw[gn0] : 0.f;
    float wv1 = ok1 ? lw[gn1] : 0.f;
    float fs = fadd ? *fsp : 0.f;
    #pragma unroll
    for (int j = 0; j < 16; ++j) {
        int gm = bm + mw*32 + (j & 3) + 8*(j >> 2) + 4*hh;
        float v0 = acc0[j] + vc0;
        float v1 = acc1[j] + vc1;
        if (fadd) {
            if (ok0) v0 += fs * fadd[(size_t)gm*400 + gn0];
            if (ok1) v1 += fs * fadd[(size_t)gm*400 + gn1];
        }
        v0 = fmaxf(v0, 0.f); v1 = fmaxf(v1, 0.f);
        if (ch) {
            if (ok0) {
                unsigned short h16, l16; split2(v0, h16, l16);
                ch[(size_t)gm*SH + gn0] = h16;
                cl[(size_t)gm*SH + gn0] = l16;
            }
            if (ok1) {
                unsigned short h16, l16; split2(v1, h16, l16);
                ch[(size_t)gm*SH + gn1] = h16;
                cl[(size_t)gm*SH + gn1] = l16;
            }
        }
        float lv = v0*wv0 + v1*wv1;
        #pragma unroll
        for (int o = 1; o < 32; o <<= 1) lv += __shfl_xor(lv, o);
        if (r31 == 0) atomicAdd(&lout[gm], lv);
    }
}

// ---------------- host ----------------
static inline size_t align64(size_t x) { return (x + 63) & ~(size_t)63; }

extern "C" void kernel_launch(void* const* d_in, const int* in_sizes, int n_in,
                              void* d_out, int out_size, void* d_ws, size_t ws_size,
                              hipStream_t stream)
{
    const float* raw_dense  = (const float*)d_in[0];
    const int*   raw_sparse = (const int*)d_in[1];
    const float* emb   = (const float*)d_in[2];
    const float* Pd    = (const float*)d_in[3];
    const float* Ps    = (const float*)d_in[4];
    const float* Pb    = (const float*)d_in[5];
    const float* Wc    = (const float*)d_in[6];
    const float* bc    = (const float*)d_in[7];
    const float* clf_w = (const float*)d_in[8];
    const float* clf_b = (const float*)d_in[9];
    const float* a0 = (const float*)d_in[10];
    const float* a1 = (const float*)d_in[11];
    const float* a2 = (const float*)d_in[12];
    const float* a3 = (const float*)d_in[13];
    float* out = (float*)d_out;

    char* p = (char*)d_ws;
    auto alloc = [&](size_t bytes) { char* r = p; p += align64(bytes); return r; };

    float* scal    = (float*)alloc(32*4);
    float* partial = (float*)alloc(2*EMB_BLOCKS*4);
    float* csd     = (float*)alloc(400*4);
    float* css     = (float*)alloc(400*4);
    float* csb     = (float*)alloc(400*4);
    float* cv      = (float*)alloc(4*448*4);
    float* gv      = (float*)alloc(4*448*4);
    float* scl2    = (float*)alloc(16*4);
    unsigned short* w0 = (unsigned short*)alloc((size_t)2*512*208*2);
    unsigned short* w1 = (unsigned short*)alloc((size_t)2*512*400*2);
    unsigned short* w2 = (unsigned short*)alloc((size_t)2*512*400*2);
    unsigned short* w3 = (unsigned short*)alloc((size_t)2*512*400*2);
    unsigned short* ws = (unsigned short*)alloc((size_t)2*512*416*2);
    float* p1 = (float*)alloc((size_t)8192*400*4);
    unsigned short* n0h = (unsigned short*)alloc((size_t)8192*SN0*2);
    unsigned short* n0l = (unsigned short*)alloc((size_t)8192*SN0*2);
    unsigned short* n1h = (unsigned short*)alloc((size_t)8192*SN1*2);
    unsigned short* n1l = (unsigned short*)alloc((size_t)8192*SN1*2);
    unsigned short* hAh = (unsigned short*)alloc((size_t)8192*SH*2);
    unsigned short* hAl = (unsigned short*)alloc((size_t)8192*SH*2);
    unsigned short* hBh = (unsigned short*)alloc((size_t)8192*SH*2);
    unsigned short* hBl = (unsigned short*)alloc((size_t)8192*SH*2);

    prep1_kernel<<<dim3(13,3),256,0,stream>>>(Pd,Ps,Pb,a0,a1,a2,a3,scal,csd,css,csb);
    embed_kernel<<<EMB_BLOCKS,256,0,stream>>>(raw_dense, raw_sparse, emb, n0h,n0l,n1h,n1l, partial);
    prepM_kernel<<<dim3(8,7,3),256,0,stream>>>(Wc,Pb,scal,w1,w2,w3);
    prep2_kernel<<<dim3(8,7,2),256,0,stream>>>(Pd,Ps,scal,w0,ws);
    prepvec_kernel<<<dim3(14,4),256,0,stream>>>(scal,csd,css,csb,Wc,bc,clf_w,Pb,cv,gv,scl2);
    finalize_kernel<<<33,256,0,stream>>>(clf_b, partial, scl2, out);

    // P1 = node1 @ Ps  (fp32, computed once, reused by all 4 h-GEMMs)
    mfma_gemm<26><<<512,256,0,stream>>>(n1h,n1l,SN1, ws, 416, nullptr, nullptr,nullptr,
                                        nullptr, nullptr, p1, nullptr, nullptr);
    // h0 = relu(node0@(s1 Pd) + s2*P1 + cv0); logits += h0@gv0
    mfma_gemm<13><<<512,256,0,stream>>>(n0h,n0l,SN0, w0, 208, cv+0,    hAh,hAl, gv+0,    out,
                                        nullptr, p1, scal+2);
    // h1 = relu(h0@M1 + s1_1*P1 + cv1); logits += h1@gv1
    mfma_gemm<25><<<512,256,0,stream>>>(hAh,hAl,SH,  w1, 400, cv+448,  hBh,hBl, gv+448,  out,
                                        nullptr, p1, scal+8+2);
    // h2
    mfma_gemm<25><<<512,256,0,stream>>>(hBh,hBl,SH,  w2, 400, cv+896,  hAh,hAl, gv+896,  out,
                                        nullptr, p1, scal+16+2);
    // h3: logits only, no store
    mfma_gemm<25><<<512,256,0,stream>>>(hAh,hAl,SH,  w3, 400, cv+1344, nullptr,nullptr, gv+1344, out,
                                        nullptr, p1, scal+24+2);
}

// Round 9
// 361.293 us; speedup vs baseline: 1.1515x; 1.1515x over previous
//
#include <hip/hip_runtime.h>
#include <cstddef>

// DynamicNetwork via split-bf16 MFMA (hi/lo, 3 MFMA per product).
// R8: algebraic fusion — nodes 2..5 never materialized.
// R15: P1 = node1@Ps computed once; h-GEMMs K 816->400. 398us best.
// R16 (reverted): de-staged GEMM — no gain; staging wasn't the cost.
// R17: WHOLE-CHAIN FUSION. The chain h_i = relu(h_{i-1}@M_i + s_i P1 + C_i) is
//   row-local in the batch dim: a block owning 32 rows runs P1,h0..h3 locally.
//   - P1 kept in REGISTERS (wave's stage-0 col-tile == its h-stage col-tile)
//   - h_{i-1} in LDS (52KB single buffer; 2 barriers/stage, 5 total)
//   - weights read as fragments direct from global (L2-resident, 3.7MB shared)
//   - logits accumulated in registers; one atomicAdd/row at the end
//   Replaces 5 GEMM dispatches + 40MB HBM intermediates with ONE dispatch.

typedef short short8 __attribute__((ext_vector_type(8)));
typedef float floatx16 __attribute__((ext_vector_type(16)));

#define EMB_BLOCKS 832
#define SN0 224   // node0 k-stride (208 used)
#define SN1 448   // node1 k-stride (416 used)

__device__ __forceinline__ unsigned short f2bf(float f) {
    unsigned int u = __float_as_uint(f);
    u += 0x7fffu + ((u >> 16) & 1u);
    return (unsigned short)(u >> 16);
}
__device__ __forceinline__ float bf2f(unsigned short h) {
    return __uint_as_float((unsigned int)h << 16);
}
__device__ __forceinline__ void split2(float v, unsigned short& h, unsigned short& l) {
    h = f2bf(v);
    l = f2bf(v - bf2f(h));
}

// ---------------- prep1: column sums (39 blocks) + alpha scalars ----------------
__global__ __launch_bounds__(256) void prep1_kernel(
    const float* __restrict__ Pd, const float* __restrict__ Ps, const float* __restrict__ Pb,
    const float* __restrict__ a0, const float* __restrict__ a1,
    const float* __restrict__ a2, const float* __restrict__ a3,
    float* __restrict__ scal,
    float* __restrict__ csd, float* __restrict__ css, float* __restrict__ csb)
{
    int t = threadIdx.x;
    int y = blockIdx.y;
    int c = t & 31, rg = t >> 5;
    int col = blockIdx.x * 32 + c;
    const float* src = (y==0) ? Pd : (y==1) ? Ps : Pb;
    int K = (y==0) ? 208 : (y==1) ? 416 : 400;
    float* out = (y==0) ? csd : (y==1) ? css : csb;
    float s = 0.f;
    if (col < 400)
        for (int k = rg; k < K; k += 8) s += src[(size_t)k*400 + col];
    __shared__ float red[8][32];
    red[rg][c] = s;
    __syncthreads();
    if (rg == 0 && col < 400) {
        float tot = 0.f;
        #pragma unroll
        for (int r = 0; r < 8; ++r) tot += red[r][c];
        out[col] = tot;
    }
    if (blockIdx.x == 0 && y == 0 && t < 4) {
        int i = t;
        const float* a = (i==0) ? a0 : (i==1) ? a1 : (i==2) ? a2 : a3;
        int np = 2 + i;
        float sum1 = 0.f, sum2 = 0.f, sumc = 0.f;
        for (int j = 0; j < np; ++j) { sum1 += a[j]; sum2 += a[np+j]; }
        for (int j = 0; j < 4; ++j) sumc += a[2*np+j];
        int i1 = (i==0) ? 0 : 1;
        int i2 = i + 1;
        int kk = i;
        float s1 = a[i1],      c1 = sum1 - s1;
        float s2 = a[np+i2],   c2 = sum2 - s2;
        float sk = a[2*np+kk], ck = sumc - sk;
        float* sl = scal + i*8;
        if (i == 0) { sl[0]=s1; sl[1]=c1; sl[2]=s2; sl[3]=c2; }
        else        { sl[0]=s2; sl[1]=c2; sl[2]=s1; sl[3]=c1; }
        sl[4] = sk; sl[5] = ck;
    }
}

// ---------------- prep2: w0 = s1*Pd (K=208) ; ws = Ps unscaled (K=416) ----------------
__global__ __launch_bounds__(256) void prep2_kernel(
    const float* __restrict__ Pd, const float* __restrict__ Ps,
    const float* __restrict__ scal,
    unsigned short* __restrict__ w0, unsigned short* __restrict__ ws)
{
    int z = blockIdx.z;
    int Kp = (z==0) ? 208 : 416;
    int Kw = Kp;
    const float* src = (z==0) ? Pd : Ps;
    unsigned short* dst = (z==0) ? w0 : ws;

    int ktiles = (Kp + 63) >> 6;
    if ((int)blockIdx.y >= ktiles) return;
    float sc = (z==0) ? scal[0] : 1.f;
    int k0 = blockIdx.y * 64, n0 = blockIdx.x * 64;
    __shared__ float T[64][65];
    int t = threadIdx.x;
    {
        int kr = t >> 2, c0 = (t & 3) * 16;
        int gk = k0 + kr;
        bool kok = gk < Kp;
        for (int j = 0; j < 16; j += 4) {
            int n = n0 + c0 + j;
            float4 v = make_float4(0.f,0.f,0.f,0.f);
            if (kok && n < 400) v = *(const float4*)&src[(size_t)gk*400 + n];
            T[kr][c0+j+0] = v.x * sc;
            T[kr][c0+j+1] = v.y * sc;
            T[kr][c0+j+2] = v.z * sc;
            T[kr][c0+j+3] = v.w * sc;
        }
    }
    __syncthreads();
    {
        int nr = t >> 2, kc0 = (t & 3) * 16;
        int gn = n0 + nr;
        int gk0 = k0 + kc0;
        if (gk0 >= Kp) return;
        unsigned short hb[16], lb[16];
        for (int j = 0; j < 16; ++j) {
            float v = (gn < 400) ? T[kc0+j][nr] : 0.f;
            split2(v, hb[j], lb[j]);
        }
        unsigned short* dh = dst + (size_t)gn*Kw + gk0;
        unsigned short* dl = dst + (size_t)512*Kw + (size_t)gn*Kw + gk0;
        *(uint4*)&dh[0] = *(uint4*)&hb[0]; *(uint4*)&dh[8] = *(uint4*)&hb[8];
        *(uint4*)&dl[0] = *(uint4*)&lb[0]; *(uint4*)&dl[8] = *(uint4*)&lb[8];
    }
}

// ---------------- prepM: M_g = s2_g * sk_{g-1} * (Wc_{g-1} @ Pb), g = z+1 ----------------
__global__ __launch_bounds__(256) void prepM_kernel(
    const float* __restrict__ Wc, const float* __restrict__ Pb,
    const float* __restrict__ scal,
    unsigned short* __restrict__ w1, unsigned short* __restrict__ w2,
    unsigned short* __restrict__ w3)
{
    int z = blockIdx.z;                   // 0..2 -> GEMM g = z+1
    unsigned short* dst = (z==0) ? w1 : (z==1) ? w2 : w3;
    const float* A = Wc + (size_t)z*5*160000;   // Wc[z, kk=z] : [400k][400j]
    float scale = scal[(z+1)*8+0] * scal[z*8+4];
    const int Kw = 400;

    __shared__ float As[16][68];   // [j][k]
    __shared__ float Ws[16][68];   // [j][n]
    int t = threadIdx.x;
    int tx = t & 15, ty = t >> 4;
    int bk = blockIdx.y * 64;
    int bn = blockIdx.x * 64;
    int arow = t >> 2;
    int aj4  = (t & 3) << 2;
    int wrow = t >> 4;
    int wc4  = (t & 15) << 2;
    float acc[4][4] = {};
    for (int j0 = 0; j0 < 400; j0 += 16) {
        float4 av = make_float4(0.f,0.f,0.f,0.f);
        if (bk + arow < 400) av = *(const float4*)&A[(size_t)(bk+arow)*400 + j0 + aj4];
        float4 wv = make_float4(0.f,0.f,0.f,0.f);
        if (bn + wc4 < 400) wv = *(const float4*)&Pb[(size_t)(j0+wrow)*400 + bn + wc4];
        __syncthreads();
        As[aj4+0][arow] = av.x;
        As[aj4+1][arow] = av.y;
        As[aj4+2][arow] = av.z;
        As[aj4+3][arow] = av.w;
        *(float4*)&Ws[wrow][wc4] = wv;
        __syncthreads();
        #pragma unroll
        for (int jj = 0; jj < 16; ++jj) {
            float4 a4 = *(const float4*)&As[jj][ty<<2];
            float4 b4 = *(const float4*)&Ws[jj][tx<<2];
            acc[0][0] += a4.x*b4.x; acc[0][1] += a4.x*b4.y; acc[0][2] += a4.x*b4.z; acc[0][3] += a4.x*b4.w;
            acc[1][0] += a4.y*b4.x; acc[1][1] += a4.y*b4.y; acc[1][2] += a4.y*b4.z; acc[1][3] += a4.y*b4.w;
            acc[2][0] += a4.z*b4.x; acc[2][1] += a4.z*b4.y; acc[2][2] += a4.z*b4.z; acc[2][3] += a4.z*b4.w;
            acc[3][0] += a4.w*b4.x; acc[3][1] += a4.w*b4.y; acc[3][2] += a4.w*b4.z; acc[3][3] += a4.w*b4.w;
        }
    }
    int gk0 = bk + (ty << 2);
    int gn0 = bn + (tx << 2);
    #pragma unroll
    for (int ik = 0; ik < 4; ++ik) {
        int gk = gk0 + ik;
        if (gk >= 400) break;
        #pragma unroll
        for (int in = 0; in < 4; ++in) {
            int gn = gn0 + in;
            float v = (gn < 400) ? acc[ik][in] * scale : 0.f;
            unsigned short h16, l16; split2(v, h16, l16);
            dst[(size_t)gn*Kw + gk] = h16;
            dst[(size_t)512*Kw + (size_t)gn*Kw + gk] = l16;
        }
    }
}

// ---------------- prepvec: C_i, gv_i, scalar consts (56 blocks) ----------------
__global__ __launch_bounds__(256) void prepvec_kernel(
    const float* __restrict__ scal,
    const float* __restrict__ csd, const float* __restrict__ css, const float* __restrict__ csb,
    const float* __restrict__ Wc, const float* __restrict__ bc,
    const float* __restrict__ clf_w, const float* __restrict__ Pb,
    float* __restrict__ cv, float* __restrict__ gv, float* __restrict__ scl2)
{
    int i = blockIdx.y;
    int tid = threadIdx.x;
    int tbase = blockIdx.x * 32;
    const float* cw = clf_w + i*400;
    float ski = scal[i*8+4], cki = scal[i*8+5];
    const float* A = Wc + (size_t)i*5*160000;

    int wv = tid >> 6, lane = tid & 63;
    #pragma unroll
    for (int q = 0; q < 8; ++q) {
        int t = tbase + wv*8 + q;
        float s = 0.f;
        if (t < 400) {
            const float* wr = A + (size_t)t*400;
            for (int j = lane; j < 400; j += 64) s += wr[j]*cw[j];
            #pragma unroll
            for (int o = 32; o > 0; o >>= 1) s += __shfl_xor(s, o);
        }
        if (lane == 0) gv[i*448 + t] = (t < 400) ? ski * s : 0.f;
    }

    __shared__ float bpred[8][32];
    int t = tbase + (tid & 31);
    int jc = tid >> 5;
    float bp_part = 0.f;
    if (i > 0 && t < 400) {
        const float* bcp = bc + (size_t)(i-1)*5*400;
        for (int j = jc*50; j < jc*50 + 50; ++j)
            bp_part += bcp[j] * Pb[(size_t)j*400 + t];
    }
    bpred[jc][tid & 31] = bp_part;
    __syncthreads();
    if (tid < 32) {
        float bp = 0.f;
        #pragma unroll
        for (int r = 0; r < 8; ++r) bp += bpred[r][tid];
        float c = 0.f;
        if (t < 400) {
            if (i == 0) {
                c = scal[1]*csd[t] + scal[3]*css[t];
            } else {
                float s2 = scal[i*8+0], c2 = scal[i*8+1];
                float c1 = scal[i*8+3];
                float skp = scal[(i-1)*8+4], ckp = scal[(i-1)*8+5];
                c = c1*css[t] + (c2 + s2*ckp)*csb[t] + s2*skp*bp;
            }
        }
        cv[i*448 + t] = c;
    }

    if (blockIdx.x == 0) {
        const float* bci = bc + (size_t)i*5*400;
        float sc = 0.f;
        for (int j = tid; j < 400; j += 256) sc += (ski*bci[j] + cki)*cw[j];
        #pragma unroll
        for (int o = 32; o > 0; o >>= 1) sc += __shfl_down(sc, o);
        __shared__ float red[4];
        int wv2 = tid >> 6, ln = tid & 63;
        if (ln == 0) red[wv2] = sc;
        __syncthreads();
        if (tid == 0) scl2[i] = red[0]+red[1]+red[2]+red[3];
    }
}

// ---------------- embed: node0/node1 bf16 hi/lo planes (padded strides) ----------------
__global__ __launch_bounds__(256) void embed_kernel(
    const float* __restrict__ rd, const int* __restrict__ rs,
    const float* __restrict__ emb,
    unsigned short* __restrict__ n0h, unsigned short* __restrict__ n0l,
    unsigned short* __restrict__ n1h, unsigned short* __restrict__ n1l,
    float* __restrict__ partial)
{
    int tid0 = blockIdx.x*256 + threadIdx.x;
    int nth = gridDim.x*256;
    float ssq = 0.f, dsq = 0.f;
    for (int it = tid0; it < 8192*26; it += nth) {
        int b = it / 26, s = it - b*26;
        int row = 13 + 50000*s + rs[b*26 + s];
        const float* e = emb + (size_t)row*16;
        float4 e0 = *(const float4*)&e[0], e1 = *(const float4*)&e[4];
        float4 e2 = *(const float4*)&e[8], e3 = *(const float4*)&e[12];
        float vv[16] = {e0.x,e0.y,e0.z,e0.w, e1.x,e1.y,e1.z,e1.w,
                        e2.x,e2.y,e2.z,e2.w, e3.x,e3.y,e3.z,e3.w};
        unsigned short hb[16], lb[16];
        for (int j = 0; j < 16; ++j) { ssq += vv[j]*vv[j]; split2(vv[j], hb[j], lb[j]); }
        size_t off = (size_t)b*SN1 + s*16;
        *(uint4*)&n1h[off] = *(uint4*)&hb[0]; *(uint4*)&n1h[off+8] = *(uint4*)&hb[8];
        *(uint4*)&n1l[off] = *(uint4*)&lb[0]; *(uint4*)&n1l[off+8] = *(uint4*)&lb[8];
    }
    for (int it = tid0; it < 8192*13; it += nth) {
        int b = it / 13, f = it - b*13;
        float sc = rd[b*13 + f];
        const float* e = emb + (size_t)f*16;
        float4 e0 = *(const float4*)&e[0], e1 = *(const float4*)&e[4];
        float4 e2 = *(const float4*)&e[8], e3 = *(const float4*)&e[12];
        float vv[16] = {e0.x,e0.y,e0.z,e0.w, e1.x,e1.y,e1.z,e1.w,
                        e2.x,e2.y,e2.z,e2.w, e3.x,e3.y,e3.z,e3.w};
        unsigned short hb[16], lb[16];
        for (int j = 0; j < 16; ++j) { float v = vv[j]*sc; dsq += v*v; split2(v, hb[j], lb[j]); }
        size_t off = (size_t)b*SN0 + f*16;
        *(uint4*)&n0h[off] = *(uint4*)&hb[0]; *(uint4*)&n0h[off+8] = *(uint4*)&hb[8];
        *(uint4*)&n0l[off] = *(uint4*)&lb[0]; *(uint4*)&n0l[off+8] = *(uint4*)&lb[8];
    }
    for (int o = 32; o > 0; o >>= 1) { ssq += __shfl_down(ssq, o); dsq += __shfl_down(dsq, o); }
    __shared__ float red[8];
    int wave = threadIdx.x >> 6, lane = threadIdx.x & 63;
    if (lane == 0) { red[wave] = dsq; red[4+wave] = ssq; }
    __syncthreads();
    if (threadIdx.x == 0) {
        partial[blockIdx.x*2]   = red[0]+red[1]+red[2]+red[3];
        partial[blockIdx.x*2+1] = red[4]+red[5]+red[6]+red[7];
    }
}

// blocks 0..31: out[b] = clf_b + sum_i scl2[i]; block 32: regs
__global__ __launch_bounds__(256) void finalize_kernel(
    const float* __restrict__ clf_b, const float* __restrict__ partial,
    const float* __restrict__ scl2, float* __restrict__ out)
{
    if (blockIdx.x < 32) {
        float base = clf_b[0] + scl2[0] + scl2[1] + scl2[2] + scl2[3];
        out[blockIdx.x*256 + threadIdx.x] = base;
        return;
    }
    float d = 0.f, s = 0.f;
    for (int i = threadIdx.x; i < EMB_BLOCKS; i += 256) { d += partial[2*i]; s += partial[2*i+1]; }
    for (int o = 32; o > 0; o >>= 1) { d += __shfl_down(d, o); s += __shfl_down(s, o); }
    __shared__ float red[8];
    int wave = threadIdx.x >> 6, lane = threadIdx.x & 63;
    if (lane == 0) { red[wave] = d; red[4+wave] = s; }
    __syncthreads();
    if (threadIdx.x == 0) {
        float dd = red[0]+red[1]+red[2]+red[3];
        float ss = red[4]+red[5]+red[6]+red[7];
        out[8192] = 1e-5f * (sqrtf(dd) + sqrtf(ss));
    }
}

// ---------------- R17 fused chain: P1 + h0..h3 + logits in ONE kernel ----------------
// Grid 256 blocks x 512 thr (8 waves). Block owns batch rows [bm, bm+32).
// Wave W owns cols [W*64, W*64+64) (2 col-tiles of 32) — SAME tile for P1 and
// every h-stage, so P1 lives in registers (p1a,p1b). h_{i-1} split bf16 in LDS
// [2][32][408] (stride 408 = 51x16B odd -> even bank distribution). Weights
// read as 16B fragments direct from global (L2-resident). Logits accumulate in
// lrow[16]; one shuffle-reduce + atomicAdd per row at the end.
#define MFMA_STEP(AH, AL, B0H, B1H, B0L, B1L, ACC0, ACC1)                      \
    ACC0 = __builtin_amdgcn_mfma_f32_32x32x16_bf16(AH, B0H, ACC0,0,0,0);       \
    ACC1 = __builtin_amdgcn_mfma_f32_32x32x16_bf16(AH, B1H, ACC1,0,0,0);       \
    ACC0 = __builtin_amdgcn_mfma_f32_32x32x16_bf16(AH, B0L, ACC0,0,0,0);       \
    ACC1 = __builtin_amdgcn_mfma_f32_32x32x16_bf16(AH, B1L, ACC1,0,0,0);       \
    ACC0 = __builtin_amdgcn_mfma_f32_32x32x16_bf16(AL, B0H, ACC0,0,0,0);       \
    ACC1 = __builtin_amdgcn_mfma_f32_32x32x16_bf16(AL, B1H, ACC1,0,0,0);

__global__ __launch_bounds__(512, 2) void fused_chain(
    const unsigned short* __restrict__ n0h, const unsigned short* __restrict__ n0l,
    const unsigned short* __restrict__ n1h, const unsigned short* __restrict__ n1l,
    const unsigned short* __restrict__ ws,
    const unsigned short* __restrict__ w0,
    const unsigned short* __restrict__ w1,
    const unsigned short* __restrict__ w2,
    const unsigned short* __restrict__ w3,
    const float* __restrict__ scal,
    const float* __restrict__ cv, const float* __restrict__ gv,
    float* __restrict__ out)
{
    __shared__ __align__(16) unsigned short hbuf[2][32][408];   // 52224 B

    int tid = threadIdx.x;
    int W = tid >> 6, lane = tid & 63;
    int r31 = lane & 31, hh = lane >> 5;
    int bm = blockIdx.x * 32;

    int gn0 = W*64 + r31;
    int gn1 = gn0 + 32;
    bool ok0 = gn0 < 400, ok1 = gn1 < 400;

    floatx16 p1a, p1b, acc0, acc1;
    float lrow[16];
    #pragma unroll
    for (int i = 0; i < 16; ++i) { p1a[i]=0.f; p1b[i]=0.f; lrow[i]=0.f; }

    // ---- stage P1: A = n1 (global), B = ws (Kw=416), nk=26 ----
    {
        const unsigned short* Ah  = n1h + (size_t)(bm + r31)*SN1 + hh*8;
        const unsigned short* Al  = n1l + (size_t)(bm + r31)*SN1 + hh*8;
        const unsigned short* B0h = ws + (size_t)gn0*416 + hh*8;
        const unsigned short* B1h = ws + (size_t)gn1*416 + hh*8;
        const unsigned short* B0l = B0h + (size_t)512*416;
        const unsigned short* B1l = B1h + (size_t)512*416;
        #pragma unroll
        for (int k = 0; k < 26; ++k) {
            short8 ah  = *(const short8*)(Ah  + k*16);
            short8 al  = *(const short8*)(Al  + k*16);
            short8 b0h = *(const short8*)(B0h + k*16);
            short8 b1h = *(const short8*)(B1h + k*16);
            short8 b0l = *(const short8*)(B0l + k*16);
            short8 b1l = *(const short8*)(B1l + k*16);
            MFMA_STEP(ah, al, b0h, b1h, b0l, b1l, p1a, p1b)
        }
    }

    // ---- epilogue helper: v = acc + cv_i + fs*P1 -> relu -> logits, h write ----
    #define H_EPILOGUE(IVEC, FS, WRITE_H)                                      \
    do {                                                                       \
        const float* cvi = cv + (IVEC)*448;                                    \
        const float* gvi = gv + (IVEC)*448;                                    \
        float vc0 = ok0 ? cvi[gn0] : 0.f;                                      \
        float vc1 = ok1 ? cvi[gn1] : 0.f;                                      \
        float wv0 = ok0 ? gvi[gn0] : 0.f;                                      \
        float wv1 = ok1 ? gvi[gn1] : 0.f;                                      \
        _Pragma("unroll")                                                      \
        for (int j = 0; j < 16; ++j) {                                         \
            int row = (j & 3) + 8*(j >> 2) + 4*hh;                             \
            float v0 = acc0[j] + vc0 + (FS)*p1a[j];                            \
            float v1 = acc1[j] + vc1 + (FS)*p1b[j];                            \
            v0 = fmaxf(v0, 0.f); v1 = fmaxf(v1, 0.f);                          \
            lrow[j] += v0*wv0 + v1*wv1;                                        \
            if (WRITE_H) {                                                     \
                unsigned short h16, l16;                                       \
                if (ok0) { split2(v0, h16, l16);                               \
                    hbuf[0][row][gn0] = h16; hbuf[1][row][gn0] = l16; }        \
                if (ok1) { split2(v1, h16, l16);                               \
                    hbuf[0][row][gn1] = h16; hbuf[1][row][gn1] = l16; }        \
            }                                                                  \
        }                                                                      \
    } while (0)

    // ---- stage h0: A = n0 (global, K=208, nk=13), B = w0 ----
    #pragma unroll
    for (int i = 0; i < 16; ++i) { acc0[i]=0.f; acc1[i]=0.f; }
    {
        const unsigned short* Ah  = n0h + (size_t)(bm + r31)*SN0 + hh*8;
        const unsigned short* Al  = n0l + (size_t)(bm + r31)*SN0 + hh*8;
        const unsigned short* B0h = w0 + (size_t)gn0*208 + hh*8;
        const unsigned short* B1h = w0 + (size_t)gn1*208 + hh*8;
        const unsigned short* B0l = B0h + (size_t)512*208;
        const unsigned short* B1l = B1h + (size_t)512*208;
        #pragma unroll
        for (int k = 0; k < 13; ++k) {
            short8 ah  = *(const short8*)(Ah  + k*16);
            short8 al  = *(const short8*)(Al  + k*16);
            short8 b0h = *(const short8*)(B0h + k*16);
            short8 b1h = *(const short8*)(B1h + k*16);
            short8 b0l = *(const short8*)(B0l + k*16);
            short8 b1l = *(const short8*)(B1l + k*16);
            MFMA_STEP(ah, al, b0h, b1h, b0l, b1l, acc0, acc1)
        }
    }
    float fs0 = scal[2];
    H_EPILOGUE(0, fs0, true);
    __syncthreads();                       // h0 visible before h1 reads

    // ---- stages h1..h3: A = hbuf (LDS, K=400, nk=25), B = w1/w2/w3 ----
    #define H_STAGE_LDS(WPTR, IVEC, FS, WRITE_H, LAST)                         \
    do {                                                                       \
        _Pragma("unroll")                                                      \
        for (int i = 0; i < 16; ++i) { acc0[i]=0.f; acc1[i]=0.f; }             \
        const unsigned short* fAh = &hbuf[0][r31][hh*8];                       \
        const unsigned short* fAl = &hbuf[1][r31][hh*8];                       \
        const unsigned short* B0h = (WPTR) + (size_t)gn0*400 + hh*8;           \
        const unsigned short* B1h = (WPTR) + (size_t)gn1*400 + hh*8;           \
        const unsigned short* B0l = B0h + (size_t)512*400;                     \
        const unsigned short* B1l = B1h + (size_t)512*400;                     \
        _Pragma("unroll")                                                      \
        for (int k = 0; k < 25; ++k) {                                         \
            short8 ah  = *(const short8*)(fAh + k*16);                         \
            short8 al  = *(const short8*)(fAl + k*16);                         \
            short8 b0h = *(const short8*)(B0h + k*16);                         \
            short8 b1h = *(const short8*)(B1h + k*16);                         \
            short8 b0l = *(const short8*)(B0l + k*16);                         \
            short8 b1l = *(const short8*)(B1l + k*16);                         \
            MFMA_STEP(ah, al, b0h, b1h, b0l, b1l, acc0, acc1)                  \
        }                                                                      \
        if (!(LAST)) __syncthreads();      /* all reads done before rewrite */ \
        H_EPILOGUE(IVEC, FS, WRITE_H);                                         \
        if (WRITE_H) __syncthreads();      /* writes visible to next stage */  \
    } while (0)

    float fs1 = scal[8+2], fs2 = scal[16+2], fs3 = scal[24+2];
    H_STAGE_LDS(w1, 1, fs1, true,  false);
    H_STAGE_LDS(w2, 2, fs2, true,  false);
    H_STAGE_LDS(w3, 3, fs3, false, true);

    #undef H_STAGE_LDS
    #undef H_EPILOGUE

    // ---- final: one atomicAdd per row ----
    #pragma unroll
    for (int j = 0; j < 16; ++j) {
        float lv = lrow[j];
        #pragma unroll
        for (int o = 1; o < 32; o <<= 1) lv += __shfl_xor(lv, o);
        if (r31 == 0) {
            int row = (j & 3) + 8*(j >> 2) + 4*hh;
            atomicAdd(&out[bm + row], lv);
        }
    }
}

// ---------------- host ----------------
static inline size_t align64(size_t x) { return (x + 63) & ~(size_t)63; }

extern "C" void kernel_launch(void* const* d_in, const int* in_sizes, int n_in,
                              void* d_out, int out_size, void* d_ws, size_t ws_size,
                              hipStream_t stream)
{
    const float* raw_dense  = (const float*)d_in[0];
    const int*   raw_sparse = (const int*)d_in[1];
    const float* emb   = (const float*)d_in[2];
    const float* Pd    = (const float*)d_in[3];
    const float* Ps    = (const float*)d_in[4];
    const float* Pb    = (const float*)d_in[5];
    const float* Wc    = (const float*)d_in[6];
    const float* bc    = (const float*)d_in[7];
    const float* clf_w = (const float*)d_in[8];
    const float* clf_b = (const float*)d_in[9];
    const float* a0 = (const float*)d_in[10];
    const float* a1 = (const float*)d_in[11];
    const float* a2 = (const float*)d_in[12];
    const float* a3 = (const float*)d_in[13];
    float* out = (float*)d_out;

    char* p = (char*)d_ws;
    auto alloc = [&](size_t bytes) { char* r = p; p += align64(bytes); return r; };

    float* scal    = (float*)alloc(32*4);
    float* partial = (float*)alloc(2*EMB_BLOCKS*4);
    float* csd     = (float*)alloc(400*4);
    float* css     = (float*)alloc(400*4);
    float* csb     = (float*)alloc(400*4);
    float* cv      = (float*)alloc(4*448*4);
    float* gv      = (float*)alloc(4*448*4);
    float* scl2    = (float*)alloc(16*4);
    unsigned short* w0 = (unsigned short*)alloc((size_t)2*512*208*2);
    unsigned short* w1 = (unsigned short*)alloc((size_t)2*512*400*2);
    unsigned short* w2 = (unsigned short*)alloc((size_t)2*512*400*2);
    unsigned short* w3 = (unsigned short*)alloc((size_t)2*512*400*2);
    unsigned short* ws = (unsigned short*)alloc((size_t)2*512*416*2);
    unsigned short* n0h = (unsigned short*)alloc((size_t)8192*SN0*2);
    unsigned short* n0l = (unsigned short*)alloc((size_t)8192*SN0*2);
    unsigned short* n1h = (unsigned short*)alloc((size_t)8192*SN1*2);
    unsigned short* n1l = (unsigned short*)alloc((size_t)8192*SN1*2);

    prep1_kernel<<<dim3(13,3),256,0,stream>>>(Pd,Ps,Pb,a0,a1,a2,a3,scal,csd,css,csb);
    embed_kernel<<<EMB_BLOCKS,256,0,stream>>>(raw_dense, raw_sparse, emb, n0h,n0l,n1h,n1l, partial);
    prepM_kernel<<<dim3(8,7,3),256,0,stream>>>(Wc,Pb,scal,w1,w2,w3);
    prep2_kernel<<<dim3(8,7,2),256,0,stream>>>(Pd,Ps,scal,w0,ws);
    prepvec_kernel<<<dim3(14,4),256,0,stream>>>(scal,csd,css,csb,Wc,bc,clf_w,Pb,cv,gv,scl2);
    finalize_kernel<<<33,256,0,stream>>>(clf_b, partial, scl2, out);

    // whole chain: P1 + h0..h3 + fused logits, one dispatch
    fused_chain<<<256,512,0,stream>>>(n0h,n0l,n1h,n1l, ws,w0,w1,w2,w3,
                                      scal, cv, gv, out);
}

// Round 10
// 315.637 us; speedup vs baseline: 1.3180x; 1.1446x over previous
//
#include <hip/hip_runtime.h>
#include <cstddef>

// DynamicNetwork via split-bf16 MFMA (hi/lo, 3 MFMA per product).
// R8: algebraic fusion — nodes 2..5 never materialized.
// R15: P1 = node1@Ps computed once; h-GEMMs K 816->400.
// R17: whole-chain fusion (P1+h0..h3+logits, one dispatch) — 361us, fused=133us.
// R18: FRAGMENT-ORDER REPACK. The ~1us/K-step constant across ALL structures
//   was uncoalesced fragment row-gathers: each 16B/lane load touched 32
//   half-used 64B lines. Weights now stored [(kb*16+nt)*64+lane]*8 and node
//   planes [(mtile*KB+kb)*64+lane]*8 so every wave fragment load is contiguous
//   1KB (16 fully-used lines). Layout-only change (same values, same order).
//   Also: 7 waves (448thr; cols 448-511 were dead), embed loop s-major so its
//   writes stay coalesced in the new layout.

typedef short short8 __attribute__((ext_vector_type(8)));
typedef float floatx16 __attribute__((ext_vector_type(16)));

#define EMB_BLOCKS 832

__device__ __forceinline__ unsigned short f2bf(float f) {
    unsigned int u = __float_as_uint(f);
    u += 0x7fffu + ((u >> 16) & 1u);
    return (unsigned short)(u >> 16);
}
__device__ __forceinline__ float bf2f(unsigned short h) {
    return __uint_as_float((unsigned int)h << 16);
}
__device__ __forceinline__ void split2(float v, unsigned short& h, unsigned short& l) {
    h = f2bf(v);
    l = f2bf(v - bf2f(h));
}

// ---------------- prep1: column sums (39 blocks) + alpha scalars ----------------
__global__ __launch_bounds__(256) void prep1_kernel(
    const float* __restrict__ Pd, const float* __restrict__ Ps, const float* __restrict__ Pb,
    const float* __restrict__ a0, const float* __restrict__ a1,
    const float* __restrict__ a2, const float* __restrict__ a3,
    float* __restrict__ scal,
    float* __restrict__ csd, float* __restrict__ css, float* __restrict__ csb)
{
    int t = threadIdx.x;
    int y = blockIdx.y;
    int c = t & 31, rg = t >> 5;
    int col = blockIdx.x * 32 + c;
    const float* src = (y==0) ? Pd : (y==1) ? Ps : Pb;
    int K = (y==0) ? 208 : (y==1) ? 416 : 400;
    float* out = (y==0) ? csd : (y==1) ? css : csb;
    float s = 0.f;
    if (col < 400)
        for (int k = rg; k < K; k += 8) s += src[(size_t)k*400 + col];
    __shared__ float red[8][32];
    red[rg][c] = s;
    __syncthreads();
    if (rg == 0 && col < 400) {
        float tot = 0.f;
        #pragma unroll
        for (int r = 0; r < 8; ++r) tot += red[r][c];
        out[col] = tot;
    }
    if (blockIdx.x == 0 && y == 0 && t < 4) {
        int i = t;
        const float* a = (i==0) ? a0 : (i==1) ? a1 : (i==2) ? a2 : a3;
        int np = 2 + i;
        float sum1 = 0.f, sum2 = 0.f, sumc = 0.f;
        for (int j = 0; j < np; ++j) { sum1 += a[j]; sum2 += a[np+j]; }
        for (int j = 0; j < 4; ++j) sumc += a[2*np+j];
        int i1 = (i==0) ? 0 : 1;
        int i2 = i + 1;
        int kk = i;
        float s1 = a[i1],      c1 = sum1 - s1;
        float s2 = a[np+i2],   c2 = sum2 - s2;
        float sk = a[2*np+kk], ck = sumc - sk;
        float* sl = scal + i*8;
        if (i == 0) { sl[0]=s1; sl[1]=c1; sl[2]=s2; sl[3]=c2; }
        else        { sl[0]=s2; sl[1]=c2; sl[2]=s1; sl[3]=c1; }
        sl[4] = sk; sl[5] = ck;
    }
}

// ---------------- prep2: w0 = s1*Pd (K=208) ; ws = Ps unscaled (K=416) ----------------
// Fragment-packed: (n,k) -> ((kb*16 + n>>5)*64 + hh8*32 + (n&31))*8 + (k&7),
// kb=k>>4, hh8=(k>>3)&1. Lo plane at +512*Kw shorts.
__global__ __launch_bounds__(256) void prep2_kernel(
    const float* __restrict__ Pd, const float* __restrict__ Ps,
    const float* __restrict__ scal,
    unsigned short* __restrict__ w0, unsigned short* __restrict__ ws)
{
    int z = blockIdx.z;
    int Kp = (z==0) ? 208 : 416;
    const float* src = (z==0) ? Pd : Ps;
    unsigned short* dst = (z==0) ? w0 : ws;
    size_t plo = (size_t)512 * Kp;

    int ktiles = (Kp + 63) >> 6;
    if ((int)blockIdx.y >= ktiles) return;
    float sc = (z==0) ? scal[0] : 1.f;
    int k0 = blockIdx.y * 64, n0 = blockIdx.x * 64;
    __shared__ float T[64][65];
    int t = threadIdx.x;
    {
        int kr = t >> 2, c0 = (t & 3) * 16;
        int gk = k0 + kr;
        bool kok = gk < Kp;
        for (int j = 0; j < 16; j += 4) {
            int n = n0 + c0 + j;
            float4 v = make_float4(0.f,0.f,0.f,0.f);
            if (kok && n < 400) v = *(const float4*)&src[(size_t)gk*400 + n];
            T[kr][c0+j+0] = v.x * sc;
            T[kr][c0+j+1] = v.y * sc;
            T[kr][c0+j+2] = v.z * sc;
            T[kr][c0+j+3] = v.w * sc;
        }
    }
    __syncthreads();
    {
        int nr = t >> 2, kc0 = (t & 3) * 16;
        int gn = n0 + nr;
        int gk0 = k0 + kc0;
        if (gk0 >= Kp) return;
        unsigned short hb[16], lb[16];
        for (int j = 0; j < 16; ++j) {
            float v = (gn < 400) ? T[kc0+j][nr] : 0.f;
            split2(v, hb[j], lb[j]);
        }
        int kb = gk0 >> 4;
        size_t off = (((size_t)kb*16 + (gn>>5))*64 + (gn&31))*8;
        *(uint4*)&dst[off]             = *(uint4*)&hb[0];   // hh8=0
        *(uint4*)&dst[off + 256]       = *(uint4*)&hb[8];   // hh8=1 (+32*8)
        *(uint4*)&dst[plo + off]       = *(uint4*)&lb[0];
        *(uint4*)&dst[plo + off + 256] = *(uint4*)&lb[8];
    }
}

// ---------------- prepM: M_g = s2_g * sk_{g-1} * (Wc_{g-1} @ Pb), g = z+1 ----------------
// Fragment-packed output (Kw=400 -> lo plane at +512*400).
__global__ __launch_bounds__(256) void prepM_kernel(
    const float* __restrict__ Wc, const float* __restrict__ Pb,
    const float* __restrict__ scal,
    unsigned short* __restrict__ w1, unsigned short* __restrict__ w2,
    unsigned short* __restrict__ w3)
{
    int z = blockIdx.z;                   // 0..2 -> GEMM g = z+1
    unsigned short* dst = (z==0) ? w1 : (z==1) ? w2 : w3;
    const float* A = Wc + (size_t)z*5*160000;   // Wc[z, kk=z] : [400k][400j]
    float scale = scal[(z+1)*8+0] * scal[z*8+4];
    const size_t plo = (size_t)512*400;

    __shared__ float As[16][68];   // [j][k]
    __shared__ float Ws[16][68];   // [j][n]
    int t = threadIdx.x;
    int tx = t & 15, ty = t >> 4;
    int bk = blockIdx.y * 64;
    int bn = blockIdx.x * 64;
    int arow = t >> 2;
    int aj4  = (t & 3) << 2;
    int wrow = t >> 4;
    int wc4  = (t & 15) << 2;
    float acc[4][4] = {};
    for (int j0 = 0; j0 < 400; j0 += 16) {
        float4 av = make_float4(0.f,0.f,0.f,0.f);
        if (bk + arow < 400) av = *(const float4*)&A[(size_t)(bk+arow)*400 + j0 + aj4];
        float4 wv = make_float4(0.f,0.f,0.f,0.f);
        if (bn + wc4 < 400) wv = *(const float4*)&Pb[(size_t)(j0+wrow)*400 + bn + wc4];
        __syncthreads();
        As[aj4+0][arow] = av.x;
        As[aj4+1][arow] = av.y;
        As[aj4+2][arow] = av.z;
        As[aj4+3][arow] = av.w;
        *(float4*)&Ws[wrow][wc4] = wv;
        __syncthreads();
        #pragma unroll
        for (int jj = 0; jj < 16; ++jj) {
            float4 a4 = *(const float4*)&As[jj][ty<<2];
            float4 b4 = *(const float4*)&Ws[jj][tx<<2];
            acc[0][0] += a4.x*b4.x; acc[0][1] += a4.x*b4.y; acc[0][2] += a4.x*b4.z; acc[0][3] += a4.x*b4.w;
            acc[1][0] += a4.y*b4.x; acc[1][1] += a4.y*b4.y; acc[1][2] += a4.y*b4.z; acc[1][3] += a4.y*b4.w;
            acc[2][0] += a4.z*b4.x; acc[2][1] += a4.z*b4.y; acc[2][2] += a4.z*b4.z; acc[2][3] += a4.z*b4.w;
            acc[3][0] += a4.w*b4.x; acc[3][1] += a4.w*b4.y; acc[3][2] += a4.w*b4.z; acc[3][3] += a4.w*b4.w;
        }
    }
    int gk0 = bk + (ty << 2);
    int gn0 = bn + (tx << 2);
    #pragma unroll
    for (int ik = 0; ik < 4; ++ik) {
        int gk = gk0 + ik;
        if (gk >= 400) break;
        int kb = gk >> 4, hh8 = (gk >> 3) & 1, e = gk & 7;
        #pragma unroll
        for (int in = 0; in < 4; ++in) {
            int gn = gn0 + in;
            float v = (gn < 400) ? acc[ik][in] * scale : 0.f;
            unsigned short h16, l16; split2(v, h16, l16);
            size_t off = (((size_t)kb*16 + (gn>>5))*64 + hh8*32 + (gn&31))*8 + e;
            dst[off] = h16;
            dst[plo + off] = l16;
        }
    }
}

// ---------------- prepvec: C_i, gv_i, scalar consts (56 blocks) ----------------
__global__ __launch_bounds__(256) void prepvec_kernel(
    const float* __restrict__ scal,
    const float* __restrict__ csd, const float* __restrict__ css, const float* __restrict__ csb,
    const float* __restrict__ Wc, const float* __restrict__ bc,
    const float* __restrict__ clf_w, const float* __restrict__ Pb,
    float* __restrict__ cv, float* __restrict__ gv, float* __restrict__ scl2)
{
    int i = blockIdx.y;
    int tid = threadIdx.x;
    int tbase = blockIdx.x * 32;
    const float* cw = clf_w + i*400;
    float ski = scal[i*8+4], cki = scal[i*8+5];
    const float* A = Wc + (size_t)i*5*160000;

    int wv = tid >> 6, lane = tid & 63;
    #pragma unroll
    for (int q = 0; q < 8; ++q) {
        int t = tbase + wv*8 + q;
        float s = 0.f;
        if (t < 400) {
            const float* wr = A + (size_t)t*400;
            for (int j = lane; j < 400; j += 64) s += wr[j]*cw[j];
            #pragma unroll
            for (int o = 32; o > 0; o >>= 1) s += __shfl_xor(s, o);
        }
        if (lane == 0) gv[i*448 + t] = (t < 400) ? ski * s : 0.f;
    }

    __shared__ float bpred[8][32];
    int t = tbase + (tid & 31);
    int jc = tid >> 5;
    float bp_part = 0.f;
    if (i > 0 && t < 400) {
        const float* bcp = bc + (size_t)(i-1)*5*400;
        for (int j = jc*50; j < jc*50 + 50; ++j)
            bp_part += bcp[j] * Pb[(size_t)j*400 + t];
    }
    bpred[jc][tid & 31] = bp_part;
    __syncthreads();
    if (tid < 32) {
        float bp = 0.f;
        #pragma unroll
        for (int r = 0; r < 8; ++r) bp += bpred[r][tid];
        float c = 0.f;
        if (t < 400) {
            if (i == 0) {
                c = scal[1]*csd[t] + scal[3]*css[t];
            } else {
                float s2 = scal[i*8+0], c2 = scal[i*8+1];
                float c1 = scal[i*8+3];
                float skp = scal[(i-1)*8+4], ckp = scal[(i-1)*8+5];
                c = c1*css[t] + (c2 + s2*ckp)*csb[t] + s2*skp*bp;
            }
        }
        cv[i*448 + t] = c;
    }

    if (blockIdx.x == 0) {
        const float* bci = bc + (size_t)i*5*400;
        float sc = 0.f;
        for (int j = tid; j < 400; j += 256) sc += (ski*bci[j] + cki)*cw[j];
        #pragma unroll
        for (int o = 32; o > 0; o >>= 1) sc += __shfl_down(sc, o);
        __shared__ float red[4];
        int wv2 = tid >> 6, ln = tid & 63;
        if (ln == 0) red[wv2] = sc;
        __syncthreads();
        if (tid == 0) scl2[i] = red[0]+red[1]+red[2]+red[3];
    }
}

// ---------------- embed: node0/node1 fragment-packed bf16 hi/lo planes ----------------
// n1: (b, s=kb) -> (((b>>5)*26 + s)*64 + hh8*32 + (b&31))*8 + e
// n0: (b, f=kb) -> (((b>>5)*13 + f)*64 + hh8*32 + (b&31))*8 + e
// Loops s/f-major so consecutive threads (consecutive b) write contiguously.
__global__ __launch_bounds__(256) void embed_kernel(
    const float* __restrict__ rd, const int* __restrict__ rs,
    const float* __restrict__ emb,
    unsigned short* __restrict__ n0h, unsigned short* __restrict__ n0l,
    unsigned short* __restrict__ n1h, unsigned short* __restrict__ n1l,
    float* __restrict__ partial)
{
    int tid0 = blockIdx.x*256 + threadIdx.x;
    int nth = gridDim.x*256;
    float ssq = 0.f, dsq = 0.f;
    for (int it = tid0; it < 8192*26; it += nth) {
        int s = it >> 13, b = it & 8191;
        int row = 13 + 50000*s + rs[b*26 + s];
        const float* e = emb + (size_t)row*16;
        float4 e0 = *(const float4*)&e[0], e1 = *(const float4*)&e[4];
        float4 e2 = *(const float4*)&e[8], e3 = *(const float4*)&e[12];
        float vv[16] = {e0.x,e0.y,e0.z,e0.w, e1.x,e1.y,e1.z,e1.w,
                        e2.x,e2.y,e2.z,e2.w, e3.x,e3.y,e3.z,e3.w};
        unsigned short hb[16], lb[16];
        for (int j = 0; j < 16; ++j) { ssq += vv[j]*vv[j]; split2(vv[j], hb[j], lb[j]); }
        size_t off = (((size_t)(b>>5)*26 + s)*64 + (b&31))*8;
        *(uint4*)&n1h[off]       = *(uint4*)&hb[0];
        *(uint4*)&n1h[off + 256] = *(uint4*)&hb[8];
        *(uint4*)&n1l[off]       = *(uint4*)&lb[0];
        *(uint4*)&n1l[off + 256] = *(uint4*)&lb[8];
    }
    for (int it = tid0; it < 8192*13; it += nth) {
        int f = it >> 13, b = it & 8191;
        float sc = rd[b*13 + f];
        const float* e = emb + (size_t)f*16;
        float4 e0 = *(const float4*)&e[0], e1 = *(const float4*)&e[4];
        float4 e2 = *(const float4*)&e[8], e3 = *(const float4*)&e[12];
        float vv[16] = {e0.x,e0.y,e0.z,e0.w, e1.x,e1.y,e1.z,e1.w,
                        e2.x,e2.y,e2.z,e2.w, e3.x,e3.y,e3.z,e3.w};
        unsigned short hb[16], lb[16];
        for (int j = 0; j < 16; ++j) { float v = vv[j]*sc; dsq += v*v; split2(v, hb[j], lb[j]); }
        size_t off = (((size_t)(b>>5)*13 + f)*64 + (b&31))*8;
        *(uint4*)&n0h[off]       = *(uint4*)&hb[0];
        *(uint4*)&n0h[off + 256] = *(uint4*)&hb[8];
        *(uint4*)&n0l[off]       = *(uint4*)&lb[0];
        *(uint4*)&n0l[off + 256] = *(uint4*)&lb[8];
    }
    for (int o = 32; o > 0; o >>= 1) { ssq += __shfl_down(ssq, o); dsq += __shfl_down(dsq, o); }
    __shared__ float red[8];
    int wave = threadIdx.x >> 6, lane = threadIdx.x & 63;
    if (lane == 0) { red[wave] = dsq; red[4+wave] = ssq; }
    __syncthreads();
    if (threadIdx.x == 0) {
        partial[blockIdx.x*2]   = red[0]+red[1]+red[2]+red[3];
        partial[blockIdx.x*2+1] = red[4]+red[5]+red[6]+red[7];
    }
}

// blocks 0..31: out[b] = clf_b + sum_i scl2[i]; block 32: regs
__global__ __launch_bounds__(256) void finalize_kernel(
    const float* __restrict__ clf_b, const float* __restrict__ partial,
    const float* __restrict__ scl2, float* __restrict__ out)
{
    if (blockIdx.x < 32) {
        float base = clf_b[0] + scl2[0] + scl2[1] + scl2[2] + scl2[3];
        out[blockIdx.x*256 + threadIdx.x] = base;
        return;
    }
    float d = 0.f, s = 0.f;
    for (int i = threadIdx.x; i < EMB_BLOCKS; i += 256) { d += partial[2*i]; s += partial[2*i+1]; }
    for (int o = 32; o > 0; o >>= 1) { d += __shfl_down(d, o); s += __shfl_down(s, o); }
    __shared__ float red[8];
    int wave = threadIdx.x >> 6, lane = threadIdx.x & 63;
    if (lane == 0) { red[wave] = d; red[4+wave] = s; }
    __syncthreads();
    if (threadIdx.x == 0) {
        float dd = red[0]+red[1]+red[2]+red[3];
        float ss = red[4]+red[5]+red[6]+red[7];
        out[8192] = 1e-5f * (sqrtf(dd) + sqrtf(ss));
    }
}

// ---------------- R18 fused chain: fragment-order operands ----------------
// Grid 256 x 448 (7 waves). Block owns rows [bm,bm+32); wave W cols [W*64,+64).
// Every fragment load = contiguous 1KB (lane*16B). B step/kb = 8192 shorts;
// A step/kb = 512 shorts. h_{i-1} in LDS as before.
#define MFMA_STEP(AH, AL, B0H, B1H, B0L, B1L, ACC0, ACC1)                      \
    ACC0 = __builtin_amdgcn_mfma_f32_32x32x16_bf16(AH, B0H, ACC0,0,0,0);       \
    ACC1 = __builtin_amdgcn_mfma_f32_32x32x16_bf16(AH, B1H, ACC1,0,0,0);       \
    ACC0 = __builtin_amdgcn_mfma_f32_32x32x16_bf16(AH, B0L, ACC0,0,0,0);       \
    ACC1 = __builtin_amdgcn_mfma_f32_32x32x16_bf16(AH, B1L, ACC1,0,0,0);       \
    ACC0 = __builtin_amdgcn_mfma_f32_32x32x16_bf16(AL, B0H, ACC0,0,0,0);       \
    ACC1 = __builtin_amdgcn_mfma_f32_32x32x16_bf16(AL, B1H, ACC1,0,0,0);

__global__ __launch_bounds__(448, 2) void fused_chain(
    const unsigned short* __restrict__ n0h, const unsigned short* __restrict__ n0l,
    const unsigned short* __restrict__ n1h, const unsigned short* __restrict__ n1l,
    const unsigned short* __restrict__ ws,
    const unsigned short* __restrict__ w0,
    const unsigned short* __restrict__ w1,
    const unsigned short* __restrict__ w2,
    const unsigned short* __restrict__ w3,
    const float* __restrict__ scal,
    const float* __restrict__ cv, const float* __restrict__ gv,
    float* __restrict__ out)
{
    __shared__ __align__(16) unsigned short hbuf[2][32][408];   // 52224 B

    int tid = threadIdx.x;
    int W = tid >> 6, lane = tid & 63;
    int r31 = lane & 31, hh = lane >> 5;
    int mtile = blockIdx.x;
    int bm = mtile * 32;

    int gn0 = W*64 + r31;
    int gn1 = gn0 + 32;
    bool ok0 = gn0 < 400, ok1 = gn1 < 400;

    floatx16 p1a, p1b, acc0, acc1;
    float lrow[16];
    #pragma unroll
    for (int i = 0; i < 16; ++i) { p1a[i]=0.f; p1b[i]=0.f; lrow[i]=0.f; }

    // ---- stage P1: A = n1 (KB=26), B = ws (Kw=416) ----
    {
        const unsigned short* Ah  = n1h + ((size_t)mtile*26*64 + lane)*8;
        const unsigned short* Al  = n1l + ((size_t)mtile*26*64 + lane)*8;
        const unsigned short* B0h = ws + ((size_t)(2*W)*64 + lane)*8;
        const unsigned short* B1h = ws + ((size_t)(2*W+1)*64 + lane)*8;
        const unsigned short* B0l = B0h + (size_t)512*416;
        const unsigned short* B1l = B1h + (size_t)512*416;
        #pragma unroll
        for (int k = 0; k < 26; ++k) {
            short8 ah  = *(const short8*)(Ah  + k*512);
            short8 al  = *(const short8*)(Al  + k*512);
            short8 b0h = *(const short8*)(B0h + k*8192);
            short8 b1h = *(const short8*)(B1h + k*8192);
            short8 b0l = *(const short8*)(B0l + k*8192);
            short8 b1l = *(const short8*)(B1l + k*8192);
            MFMA_STEP(ah, al, b0h, b1h, b0l, b1l, p1a, p1b)
        }
    }

    // ---- epilogue helper: v = acc + cv_i + fs*P1 -> relu -> logits, h write ----
    #define H_EPILOGUE(IVEC, FS, WRITE_H)                                      \
    do {                                                                       \
        const float* cvi = cv + (IVEC)*448;                                    \
        const float* gvi = gv + (IVEC)*448;                                    \
        float vc0 = ok0 ? cvi[gn0] : 0.f;                                      \
        float vc1 = ok1 ? cvi[gn1] : 0.f;                                      \
        float wv0 = ok0 ? gvi[gn0] : 0.f;                                      \
        float wv1 = ok1 ? gvi[gn1] : 0.f;                                      \
        _Pragma("unroll")                                                      \
        for (int j = 0; j < 16; ++j) {                                         \
            int row = (j & 3) + 8*(j >> 2) + 4*hh;                             \
            float v0 = acc0[j] + vc0 + (FS)*p1a[j];                            \
            float v1 = acc1[j] + vc1 + (FS)*p1b[j];                            \
            v0 = fmaxf(v0, 0.f); v1 = fmaxf(v1, 0.f);                          \
            lrow[j] += v0*wv0 + v1*wv1;                                        \
            if (WRITE_H) {                                                     \
                unsigned short h16, l16;                                       \
                if (ok0) { split2(v0, h16, l16);                               \
                    hbuf[0][row][gn0] = h16; hbuf[1][row][gn0] = l16; }        \
                if (ok1) { split2(v1, h16, l16);                               \
                    hbuf[0][row][gn1] = h16; hbuf[1][row][gn1] = l16; }        \
            }                                                                  \
        }                                                                      \
    } while (0)

    // ---- stage h0: A = n0 (KB=13), B = w0 (Kw=208) ----
    #pragma unroll
    for (int i = 0; i < 16; ++i) { acc0[i]=0.f; acc1[i]=0.f; }
    {
        const unsigned short* Ah  = n0h + ((size_t)mtile*13*64 + lane)*8;
        const unsigned short* Al  = n0l + ((size_t)mtile*13*64 + lane)*8;
        const unsigned short* B0h = w0 + ((size_t)(2*W)*64 + lane)*8;
        const unsigned short* B1h = w0 + ((size_t)(2*W+1)*64 + lane)*8;
        const unsigned short* B0l = B0h + (size_t)512*208;
        const unsigned short* B1l = B1h + (size_t)512*208;
        #pragma unroll
        for (int k = 0; k < 13; ++k) {
            short8 ah  = *(const short8*)(Ah  + k*512);
            short8 al  = *(const short8*)(Al  + k*512);
            short8 b0h = *(const short8*)(B0h + k*8192);
            short8 b1h = *(const short8*)(B1h + k*8192);
            short8 b0l = *(const short8*)(B0l + k*8192);
            short8 b1l = *(const short8*)(B1l + k*8192);
            MFMA_STEP(ah, al, b0h, b1h, b0l, b1l, acc0, acc1)
        }
    }
    float fs0 = scal[2];
    H_EPILOGUE(0, fs0, true);
    __syncthreads();                       // h0 visible before h1 reads

    // ---- stages h1..h3: A = hbuf (LDS, nk=25), B = w1/w2/w3 (Kw=400) ----
    #define H_STAGE_LDS(WPTR, IVEC, FS, WRITE_H, LAST)                         \
    do {                                                                       \
        _Pragma("unroll")                                                      \
        for (int i = 0; i < 16; ++i) { acc0[i]=0.f; acc1[i]=0.f; }             \
        const unsigned short* fAh = &hbuf[0][r31][hh*8];                       \
        const unsigned short* fAl = &hbuf[1][r31][hh*8];                       \
        const unsigned short* B0h = (WPTR) + ((size_t)(2*W)*64 + lane)*8;      \
        const unsigned short* B1h = (WPTR) + ((size_t)(2*W+1)*64 + lane)*8;    \
        const unsigned short* B0l = B0h + (size_t)512*400;                     \
        const unsigned short* B1l = B1h + (size_t)512*400;                     \
        _Pragma("unroll")                                                      \
        for (int k = 0; k < 25; ++k) {                                         \
            short8 ah  = *(const short8*)(fAh + k*16);                         \
            short8 al  = *(const short8*)(fAl + k*16);                         \
            short8 b0h = *(const short8*)(B0h + k*8192);                       \
            short8 b1h = *(const short8*)(B1h + k*8192);                       \
            short8 b0l = *(const short8*)(B0l + k*8192);                       \
            short8 b1l = *(const short8*)(B1l + k*8192);                       \
            MFMA_STEP(ah, al, b0h, b1h, b0l, b1l, acc0, acc1)                  \
        }                                                                      \
        if (!(LAST)) __syncthreads();      /* all reads done before rewrite */ \
        H_EPILOGUE(IVEC, FS, WRITE_H);                                         \
        if (WRITE_H) __syncthreads();      /* writes visible to next stage */  \
    } while (0)

    float fs1 = scal[8+2], fs2 = scal[16+2], fs3 = scal[24+2];
    H_STAGE_LDS(w1, 1, fs1, true,  false);
    H_STAGE_LDS(w2, 2, fs2, true,  false);
    H_STAGE_LDS(w3, 3, fs3, false, true);

    #undef H_STAGE_LDS
    #undef H_EPILOGUE

    // ---- final: one atomicAdd per row ----
    #pragma unroll
    for (int j = 0; j < 16; ++j) {
        float lv = lrow[j];
        #pragma unroll
        for (int o = 1; o < 32; o <<= 1) lv += __shfl_xor(lv, o);
        if (r31 == 0) {
            int row = (j & 3) + 8*(j >> 2) + 4*hh;
            atomicAdd(&out[bm + row], lv);
        }
    }
}

// ---------------- host ----------------
static inline size_t align64(size_t x) { return (x + 63) & ~(size_t)63; }

extern "C" void kernel_launch(void* const* d_in, const int* in_sizes, int n_in,
                              void* d_out, int out_size, void* d_ws, size_t ws_size,
                              hipStream_t stream)
{
    const float* raw_dense  = (const float*)d_in[0];
    const int*   raw_sparse = (const int*)d_in[1];
    const float* emb   = (const float*)d_in[2];
    const float* Pd    = (const float*)d_in[3];
    const float* Ps    = (const float*)d_in[4];
    const float* Pb    = (const float*)d_in[5];
    const float* Wc    = (const float*)d_in[6];
    const float* bc    = (const float*)d_in[7];
    const float* clf_w = (const float*)d_in[8];
    const float* clf_b = (const float*)d_in[9];
    const float* a0 = (const float*)d_in[10];
    const float* a1 = (const float*)d_in[11];
    const float* a2 = (const float*)d_in[12];
    const float* a3 = (const float*)d_in[13];
    float* out = (float*)d_out;

    char* p = (char*)d_ws;
    auto alloc = [&](size_t bytes) { char* r = p; p += align64(bytes); return r; };

    float* scal    = (float*)alloc(32*4);
    float* partial = (float*)alloc(2*EMB_BLOCKS*4);
    float* csd     = (float*)alloc(400*4);
    float* css     = (float*)alloc(400*4);
    float* csb     = (float*)alloc(400*4);
    float* cv      = (float*)alloc(4*448*4);
    float* gv      = (float*)alloc(4*448*4);
    float* scl2    = (float*)alloc(16*4);
    unsigned short* w0 = (unsigned short*)alloc((size_t)2*512*208*2);
    unsigned short* w1 = (unsigned short*)alloc((size_t)2*512*400*2);
    unsigned short* w2 = (unsigned short*)alloc((size_t)2*512*400*2);
    unsigned short* w3 = (unsigned short*)alloc((size_t)2*512*400*2);
    unsigned short* ws = (unsigned short*)alloc((size_t)2*512*416*2);
    unsigned short* n0h = (unsigned short*)alloc((size_t)256*13*512*2);
    unsigned short* n0l = (unsigned short*)alloc((size_t)256*13*512*2);
    unsigned short* n1h = (unsigned short*)alloc((size_t)256*26*512*2);
    unsigned short* n1l = (unsigned short*)alloc((size_t)256*26*512*2);

    prep1_kernel<<<dim3(13,3),256,0,stream>>>(Pd,Ps,Pb,a0,a1,a2,a3,scal,csd,css,csb);
    embed_kernel<<<EMB_BLOCKS,256,0,stream>>>(raw_dense, raw_sparse, emb, n0h,n0l,n1h,n1l, partial);
    prepM_kernel<<<dim3(8,7,3),256,0,stream>>>(Wc,Pb,scal,w1,w2,w3);
    prep2_kernel<<<dim3(8,7,2),256,0,stream>>>(Pd,Ps,scal,w0,ws);
    prepvec_kernel<<<dim3(14,4),256,0,stream>>>(scal,csd,css,csb,Wc,bc,clf_w,Pb,cv,gv,scl2);
    finalize_kernel<<<33,256,0,stream>>>(clf_b, partial, scl2, out);

    // whole chain: P1 + h0..h3 + fused logits, one dispatch
    fused_chain<<<256,448,0,stream>>>(n0h,n0l,n1h,n1l, ws,w0,w1,w2,w3,
                                      scal, cv, gv, out);
}

// Round 11
// 263.453 us; speedup vs baseline: 1.5791x; 1.1981x over previous
//
#include <hip/hip_runtime.h>
#include <cstddef>

// DynamicNetwork via split-bf16 MFMA (hi/lo, 3 MFMA per product).
// R8: algebraic fusion — nodes 2..5 never materialized.
// R15: P1 = node1@Ps computed once; h-GEMMs K 816->400.
// R17: whole-chain fusion (P1+h0..h3+logits, one dispatch).
// R18: fragment-order repack (coalesced 1KB wave loads) — 316us, fused=81us.
// R19: (a) K-SPLIT 14-WAVE fused chain: wave = (coltile c 0..6, kw 0..1);
//   kw0 takes even kb, kw1 odd kb; partials merged via LDS pbuf at each stage
//   (barriers already existed). TLP 7 -> 14 waves (occupancy 18% -> ~40%).
//   (b) MEGA-PREP: embed+prep1+prep2+prepM are independent once prep2/prepM
//   read their 2 alpha scalars directly from a0..a3 -> one 1151-block dispatch
//   (was 4 serial). Chain: mega -> prepvec -> finalize -> fused (4 dispatches).

typedef short short8 __attribute__((ext_vector_type(8)));
typedef float floatx16 __attribute__((ext_vector_type(16)));

#define EMB_BLOCKS 832

__device__ __forceinline__ unsigned short f2bf(float f) {
    unsigned int u = __float_as_uint(f);
    u += 0x7fffu + ((u >> 16) & 1u);
    return (unsigned short)(u >> 16);
}
__device__ __forceinline__ float bf2f(unsigned short h) {
    return __uint_as_float((unsigned int)h << 16);
}
__device__ __forceinline__ void split2(float v, unsigned short& h, unsigned short& l) {
    h = f2bf(v);
    l = f2bf(v - bf2f(h));
}

// ---------------- mega_prep: embed(832) + prep1(39) + prep2(112) + prepM(168) ----------------
__global__ __launch_bounds__(256) void mega_prep(
    const float* __restrict__ rd, const int* __restrict__ rs,
    const float* __restrict__ emb,
    const float* __restrict__ Pd, const float* __restrict__ Ps, const float* __restrict__ Pb,
    const float* __restrict__ Wc,
    const float* __restrict__ a0, const float* __restrict__ a1,
    const float* __restrict__ a2, const float* __restrict__ a3,
    float* __restrict__ scal,
    float* __restrict__ csd, float* __restrict__ css, float* __restrict__ csb,
    unsigned short* __restrict__ w0, unsigned short* __restrict__ ws,
    unsigned short* __restrict__ w1, unsigned short* __restrict__ w2,
    unsigned short* __restrict__ w3,
    unsigned short* __restrict__ n0h, unsigned short* __restrict__ n0l,
    unsigned short* __restrict__ n1h, unsigned short* __restrict__ n1l,
    float* __restrict__ partial)
{
    __shared__ __align__(16) float smem[64*65];   // 16640B, unioned across roles
    int bid = blockIdx.x;
    int t = threadIdx.x;

    if (bid < 832) {
        // ---------------- embed role (fragment-packed outputs) ----------------
        int tid0 = bid*256 + t;
        const int nth = 832*256;
        float ssq = 0.f, dsq = 0.f;
        for (int it = tid0; it < 8192*26; it += nth) {
            int s = it >> 13, b = it & 8191;
            int row = 13 + 50000*s + rs[b*26 + s];
            const float* e = emb + (size_t)row*16;
            float4 e0 = *(const float4*)&e[0], e1 = *(const float4*)&e[4];
            float4 e2 = *(const float4*)&e[8], e3 = *(const float4*)&e[12];
            float vv[16] = {e0.x,e0.y,e0.z,e0.w, e1.x,e1.y,e1.z,e1.w,
                            e2.x,e2.y,e2.z,e2.w, e3.x,e3.y,e3.z,e3.w};
            unsigned short hb[16], lb[16];
            for (int j = 0; j < 16; ++j) { ssq += vv[j]*vv[j]; split2(vv[j], hb[j], lb[j]); }
            size_t off = (((size_t)(b>>5)*26 + s)*64 + (b&31))*8;
            *(uint4*)&n1h[off]       = *(uint4*)&hb[0];
            *(uint4*)&n1h[off + 256] = *(uint4*)&hb[8];
            *(uint4*)&n1l[off]       = *(uint4*)&lb[0];
            *(uint4*)&n1l[off + 256] = *(uint4*)&lb[8];
        }
        for (int it = tid0; it < 8192*13; it += nth) {
            int f = it >> 13, b = it & 8191;
            float sc = rd[b*13 + f];
            const float* e = emb + (size_t)f*16;
            float4 e0 = *(const float4*)&e[0], e1 = *(const float4*)&e[4];
            float4 e2 = *(const float4*)&e[8], e3 = *(const float4*)&e[12];
            float vv[16] = {e0.x,e0.y,e0.z,e0.w, e1.x,e1.y,e1.z,e1.w,
                            e2.x,e2.y,e2.z,e2.w, e3.x,e3.y,e3.z,e3.w};
            unsigned short hb[16], lb[16];
            for (int j = 0; j < 16; ++j) { float v = vv[j]*sc; dsq += v*v; split2(v, hb[j], lb[j]); }
            size_t off = (((size_t)(b>>5)*13 + f)*64 + (b&31))*8;
            *(uint4*)&n0h[off]       = *(uint4*)&hb[0];
            *(uint4*)&n0h[off + 256] = *(uint4*)&hb[8];
            *(uint4*)&n0l[off]       = *(uint4*)&lb[0];
            *(uint4*)&n0l[off + 256] = *(uint4*)&lb[8];
        }
        for (int o = 32; o > 0; o >>= 1) { ssq += __shfl_down(ssq, o); dsq += __shfl_down(dsq, o); }
        float* red = smem;
        int wave = t >> 6, lane = t & 63;
        if (lane == 0) { red[wave] = dsq; red[4+wave] = ssq; }
        __syncthreads();
        if (t == 0) {
            partial[bid*2]   = red[0]+red[1]+red[2]+red[3];
            partial[bid*2+1] = red[4]+red[5]+red[6]+red[7];
        }
        return;
    }
    if (bid < 871) {
        // ---------------- prep1 role: column sums + alpha scalars ----------------
        int r = bid - 832;
        int x = r % 13, y = r / 13;
        int c = t & 31, rg = t >> 5;
        int col = x * 32 + c;
        const float* src = (y==0) ? Pd : (y==1) ? Ps : Pb;
        int K = (y==0) ? 208 : (y==1) ? 416 : 400;
        float* outp = (y==0) ? csd : (y==1) ? css : csb;
        float s = 0.f;
        if (col < 400)
            for (int k = rg; k < K; k += 8) s += src[(size_t)k*400 + col];
        float (*red)[32] = (float(*)[32])smem;
        red[rg][c] = s;
        __syncthreads();
        if (rg == 0 && col < 400) {
            float tot = 0.f;
            #pragma unroll
            for (int rr = 0; rr < 8; ++rr) tot += red[rr][c];
            outp[col] = tot;
        }
        if (x == 0 && y == 0 && t < 4) {
            int i = t;
            const float* a = (i==0) ? a0 : (i==1) ? a1 : (i==2) ? a2 : a3;
            int np = 2 + i;
            float sum1 = 0.f, sum2 = 0.f, sumc = 0.f;
            for (int j = 0; j < np; ++j) { sum1 += a[j]; sum2 += a[np+j]; }
            for (int j = 0; j < 4; ++j) sumc += a[2*np+j];
            int i1 = (i==0) ? 0 : 1;
            int i2 = i + 1;
            int kk = i;
            float s1 = a[i1],      c1 = sum1 - s1;
            float s2 = a[np+i2],   c2 = sum2 - s2;
            float sk = a[2*np+kk], ck = sumc - sk;
            float* sl = scal + i*8;
            if (i == 0) { sl[0]=s1; sl[1]=c1; sl[2]=s2; sl[3]=c2; }
            else        { sl[0]=s2; sl[1]=c2; sl[2]=s1; sl[3]=c1; }
            sl[4] = sk; sl[5] = ck;
        }
        return;
    }
    if (bid < 983) {
        // ---------------- prep2 role: w0 = s1*Pd (K=208); ws = Ps (K=416) ----------------
        int r = bid - 871;
        int z = r / 56, rem = r % 56;
        int y = rem / 8, x = rem % 8;
        int Kp = (z==0) ? 208 : 416;
        const float* src = (z==0) ? Pd : Ps;
        unsigned short* dst = (z==0) ? w0 : ws;
        size_t plo = (size_t)512 * Kp;
        int ktiles = (Kp + 63) >> 6;
        if (y >= ktiles) return;
        float sc = (z==0) ? a0[0] : 1.f;       // s1 for i=0 is a0[i1=0]
        int k0 = y * 64, n0 = x * 64;
        float (*T)[65] = (float(*)[65])smem;
        {
            int kr = t >> 2, c0 = (t & 3) * 16;
            int gk = k0 + kr;
            bool kok = gk < Kp;
            for (int j = 0; j < 16; j += 4) {
                int n = n0 + c0 + j;
                float4 v = make_float4(0.f,0.f,0.f,0.f);
                if (kok && n < 400) v = *(const float4*)&src[(size_t)gk*400 + n];
                T[kr][c0+j+0] = v.x * sc;
                T[kr][c0+j+1] = v.y * sc;
                T[kr][c0+j+2] = v.z * sc;
                T[kr][c0+j+3] = v.w * sc;
            }
        }
        __syncthreads();
        {
            int nr = t >> 2, kc0 = (t & 3) * 16;
            int gn = n0 + nr;
            int gk0 = k0 + kc0;
            if (gk0 >= Kp) return;
            unsigned short hb[16], lb[16];
            for (int j = 0; j < 16; ++j) {
                float v = (gn < 400) ? T[kc0+j][nr] : 0.f;
                split2(v, hb[j], lb[j]);
            }
            int kb = gk0 >> 4;
            size_t off = (((size_t)kb*16 + (gn>>5))*64 + (gn&31))*8;
            *(uint4*)&dst[off]             = *(uint4*)&hb[0];
            *(uint4*)&dst[off + 256]       = *(uint4*)&hb[8];
            *(uint4*)&dst[plo + off]       = *(uint4*)&lb[0];
            *(uint4*)&dst[plo + off + 256] = *(uint4*)&lb[8];
        }
        return;
    }
    {
        // ---------------- prepM role: M_g fragment-packed ----------------
        int r = bid - 983;
        int z = r / 56, rem = r % 56;
        int by = rem / 8, bx = rem % 8;
        unsigned short* dst = (z==0) ? w1 : (z==1) ? w2 : w3;
        const float* A = Wc + (size_t)z*5*160000;
        // scale = s2_{z+1} * sk_z = a_{z+1}[2z+5] * a_z[3z+4]
        const float* az1 = (z==0) ? a1 : (z==1) ? a2 : a3;
        const float* az  = (z==0) ? a0 : (z==1) ? a1 : a2;
        float scale = az1[2*z+5] * az[3*z+4];
        const size_t plo = (size_t)512*400;

        float (*As)[68] = (float(*)[68])smem;          // 16 rows
        float (*Ws)[68] = (float(*)[68])(smem + 16*68); // 16 rows
        int tx = t & 15, ty = t >> 4;
        int bk = by * 64;
        int bn = bx * 64;
        int arow = t >> 2;
        int aj4  = (t & 3) << 2;
        int wrow = t >> 4;
        int wc4  = (t & 15) << 2;
        float acc[4][4] = {};
        for (int j0 = 0; j0 < 400; j0 += 16) {
            float4 av = make_float4(0.f,0.f,0.f,0.f);
            if (bk + arow < 400) av = *(const float4*)&A[(size_t)(bk+arow)*400 + j0 + aj4];
            float4 wv = make_float4(0.f,0.f,0.f,0.f);
            if (bn + wc4 < 400) wv = *(const float4*)&Pb[(size_t)(j0+wrow)*400 + bn + wc4];
            __syncthreads();
            As[aj4+0][arow] = av.x;
            As[aj4+1][arow] = av.y;
            As[aj4+2][arow] = av.z;
            As[aj4+3][arow] = av.w;
            *(float4*)&Ws[wrow][wc4] = wv;
            __syncthreads();
            #pragma unroll
            for (int jj = 0; jj < 16; ++jj) {
                float4 a4 = *(const float4*)&As[jj][ty<<2];
                float4 b4 = *(const float4*)&Ws[jj][tx<<2];
                acc[0][0] += a4.x*b4.x; acc[0][1] += a4.x*b4.y; acc[0][2] += a4.x*b4.z; acc[0][3] += a4.x*b4.w;
                acc[1][0] += a4.y*b4.x; acc[1][1] += a4.y*b4.y; acc[1][2] += a4.y*b4.z; acc[1][3] += a4.y*b4.w;
                acc[2][0] += a4.z*b4.x; acc[2][1] += a4.z*b4.y; acc[2][2] += a4.z*b4.z; acc[2][3] += a4.z*b4.w;
                acc[3][0] += a4.w*b4.x; acc[3][1] += a4.w*b4.y; acc[3][2] += a4.w*b4.z; acc[3][3] += a4.w*b4.w;
            }
        }
        int gk0 = bk + (ty << 2);
        int gn0 = bn + (tx << 2);
        #pragma unroll
        for (int ik = 0; ik < 4; ++ik) {
            int gk = gk0 + ik;
            if (gk >= 400) break;
            int kb = gk >> 4, hh8 = (gk >> 3) & 1, e = gk & 7;
            #pragma unroll
            for (int in = 0; in < 4; ++in) {
                int gn = gn0 + in;
                float v = (gn < 400) ? acc[ik][in] * scale : 0.f;
                unsigned short h16, l16; split2(v, h16, l16);
                size_t off = (((size_t)kb*16 + (gn>>5))*64 + hh8*32 + (gn&31))*8 + e;
                dst[off] = h16;
                dst[plo + off] = l16;
            }
        }
    }
}

// ---------------- prepvec: C_i, gv_i, scalar consts (56 blocks) ----------------
__global__ __launch_bounds__(256) void prepvec_kernel(
    const float* __restrict__ scal,
    const float* __restrict__ csd, const float* __restrict__ css, const float* __restrict__ csb,
    const float* __restrict__ Wc, const float* __restrict__ bc,
    const float* __restrict__ clf_w, const float* __restrict__ Pb,
    float* __restrict__ cv, float* __restrict__ gv, float* __restrict__ scl2)
{
    int i = blockIdx.y;
    int tid = threadIdx.x;
    int tbase = blockIdx.x * 32;
    const float* cw = clf_w + i*400;
    float ski = scal[i*8+4], cki = scal[i*8+5];
    const float* A = Wc + (size_t)i*5*160000;

    int wv = tid >> 6, lane = tid & 63;
    #pragma unroll
    for (int q = 0; q < 8; ++q) {
        int t = tbase + wv*8 + q;
        float s = 0.f;
        if (t < 400) {
            const float* wr = A + (size_t)t*400;
            for (int j = lane; j < 400; j += 64) s += wr[j]*cw[j];
            #pragma unroll
            for (int o = 32; o > 0; o >>= 1) s += __shfl_xor(s, o);
        }
        if (lane == 0) gv[i*448 + t] = (t < 400) ? ski * s : 0.f;
    }

    __shared__ float bpred[8][32];
    int t = tbase + (tid & 31);
    int jc = tid >> 5;
    float bp_part = 0.f;
    if (i > 0 && t < 400) {
        const float* bcp = bc + (size_t)(i-1)*5*400;
        for (int j = jc*50; j < jc*50 + 50; ++j)
            bp_part += bcp[j] * Pb[(size_t)j*400 + t];
    }
    bpred[jc][tid & 31] = bp_part;
    __syncthreads();
    if (tid < 32) {
        float bp = 0.f;
        #pragma unroll
        for (int r = 0; r < 8; ++r) bp += bpred[r][tid];
        float c = 0.f;
        if (t < 400) {
            if (i == 0) {
                c = scal[1]*csd[t] + scal[3]*css[t];
            } else {
                float s2 = scal[i*8+0], c2 = scal[i*8+1];
                float c1 = scal[i*8+3];
                float skp = scal[(i-1)*8+4], ckp = scal[(i-1)*8+5];
                c = c1*css[t] + (c2 + s2*ckp)*csb[t] + s2*skp*bp;
            }
        }
        cv[i*448 + t] = c;
    }

    if (blockIdx.x == 0) {
        const float* bci = bc + (size_t)i*5*400;
        float sc = 0.f;
        for (int j = tid; j < 400; j += 256) sc += (ski*bci[j] + cki)*cw[j];
        #pragma unroll
        for (int o = 32; o > 0; o >>= 1) sc += __shfl_down(sc, o);
        __shared__ float red[4];
        int wv2 = tid >> 6, ln = tid & 63;
        if (ln == 0) red[wv2] = sc;
        __syncthreads();
        if (tid == 0) scl2[i] = red[0]+red[1]+red[2]+red[3];
    }
}

// blocks 0..31: out[b] = clf_b + sum_i scl2[i]; block 32: regs
__global__ __launch_bounds__(256) void finalize_kernel(
    const float* __restrict__ clf_b, const float* __restrict__ partial,
    const float* __restrict__ scl2, float* __restrict__ out)
{
    if (blockIdx.x < 32) {
        float base = clf_b[0] + scl2[0] + scl2[1] + scl2[2] + scl2[3];
        out[blockIdx.x*256 + threadIdx.x] = base;
        return;
    }
    float d = 0.f, s = 0.f;
    for (int i = threadIdx.x; i < EMB_BLOCKS; i += 256) { d += partial[2*i]; s += partial[2*i+1]; }
    for (int o = 32; o > 0; o >>= 1) { d += __shfl_down(d, o); s += __shfl_down(s, o); }
    __shared__ float red[8];
    int wave = threadIdx.x >> 6, lane = threadIdx.x & 63;
    if (lane == 0) { red[wave] = d; red[4+wave] = s; }
    __syncthreads();
    if (threadIdx.x == 0) {
        float dd = red[0]+red[1]+red[2]+red[3];
        float ss = red[4]+red[5]+red[6]+red[7];
        out[8192] = 1e-5f * (sqrtf(dd) + sqrtf(ss));
    }
}

// ---------------- R19 fused chain: 14 waves, k-split pairs ----------------
// Grid 256 x 896 (14 waves). Wave = (c = W%7 col-tile, kw = W/7 k-half).
// kw0 computes even kb, kw1 odd kb; kw1 writes partials to pbuf; kw0 merges,
// does the epilogue (hbuf writes, lrow, atomics). Barriers per stage: 2.
#define MFMA_STEP(AH, AL, B0H, B1H, B0L, B1L, ACC0, ACC1)                      \
    ACC0 = __builtin_amdgcn_mfma_f32_32x32x16_bf16(AH, B0H, ACC0,0,0,0);       \
    ACC1 = __builtin_amdgcn_mfma_f32_32x32x16_bf16(AH, B1H, ACC1,0,0,0);       \
    ACC0 = __builtin_amdgcn_mfma_f32_32x32x16_bf16(AH, B0L, ACC0,0,0,0);       \
    ACC1 = __builtin_amdgcn_mfma_f32_32x32x16_bf16(AH, B1L, ACC1,0,0,0);       \
    ACC0 = __builtin_amdgcn_mfma_f32_32x32x16_bf16(AL, B0H, ACC0,0,0,0);       \
    ACC1 = __builtin_amdgcn_mfma_f32_32x32x16_bf16(AL, B1H, ACC1,0,0,0);

__global__ __launch_bounds__(896, 4) void fused_chain(
    const unsigned short* __restrict__ n0h, const unsigned short* __restrict__ n0l,
    const unsigned short* __restrict__ n1h, const unsigned short* __restrict__ n1l,
    const unsigned short* __restrict__ ws,
    const unsigned short* __restrict__ w0,
    const unsigned short* __restrict__ w1,
    const unsigned short* __restrict__ w2,
    const unsigned short* __restrict__ w3,
    const float* __restrict__ scal,
    const float* __restrict__ cv, const float* __restrict__ gv,
    float* __restrict__ out)
{
    __shared__ __align__(16) unsigned short hbuf[2][32][408];   // 52224 B
    __shared__ __align__(16) float pbuf[14][64][16];            // 57344 B

    int tid = threadIdx.x;
    int W = tid >> 6, lane = tid & 63;
    int r31 = lane & 31, hh = lane >> 5;
    int c = W % 7, kw = W / 7;
    int mtile = blockIdx.x;
    int bm = mtile * 32;

    int gn0 = c*64 + r31;
    int gn1 = gn0 + 32;
    bool ok0 = gn0 < 400, ok1 = gn1 < 400;

    floatx16 p1a, p1b, acc0, acc1;
    float lrow[16];
    #pragma unroll
    for (int i = 0; i < 16; ++i) { p1a[i]=0.f; p1b[i]=0.f; lrow[i]=0.f; }

    #define PBUF_WRITE(V0, V1)                                                 \
    do {                                                                       \
        _Pragma("unroll")                                                      \
        for (int j4 = 0; j4 < 4; ++j4) {                                       \
            *(float4*)&pbuf[2*c  ][lane][j4*4] =                               \
                make_float4(V0[j4*4+0],V0[j4*4+1],V0[j4*4+2],V0[j4*4+3]);      \
            *(float4*)&pbuf[2*c+1][lane][j4*4] =                               \
                make_float4(V1[j4*4+0],V1[j4*4+1],V1[j4*4+2],V1[j4*4+3]);      \
        }                                                                      \
    } while (0)

    #define PBUF_MERGE(V0, V1)                                                 \
    do {                                                                       \
        _Pragma("unroll")                                                      \
        for (int j = 0; j < 16; ++j) {                                         \
            V0[j] += pbuf[2*c][lane][j];                                       \
            V1[j] += pbuf[2*c+1][lane][j];                                     \
        }                                                                      \
    } while (0)

    // ---- stage P1: A = n1 (NK=26 -> 13/13), B = ws (Kw=416) ----
    {
        const unsigned short* Ah  = n1h + ((size_t)mtile*26*64 + lane)*8 + kw*512;
        const unsigned short* Al  = n1l + ((size_t)mtile*26*64 + lane)*8 + kw*512;
        const unsigned short* B0h = ws + ((size_t)(2*c)*64 + lane)*8 + (size_t)kw*8192;
        const unsigned short* B1h = ws + ((size_t)(2*c+1)*64 + lane)*8 + (size_t)kw*8192;
        const unsigned short* B0l = B0h + (size_t)512*416;
        const unsigned short* B1l = B1h + (size_t)512*416;
        #pragma unroll
        for (int kq = 0; kq < 13; ++kq) {
            short8 ah  = *(const short8*)(Ah  + kq*1024);
            short8 al  = *(const short8*)(Al  + kq*1024);
            short8 b0h = *(const short8*)(B0h + kq*16384);
            short8 b1h = *(const short8*)(B1h + kq*16384);
            short8 b0l = *(const short8*)(B0l + kq*16384);
            short8 b1l = *(const short8*)(B1l + kq*16384);
            MFMA_STEP(ah, al, b0h, b1h, b0l, b1l, p1a, p1b)
        }
    }
    if (kw) PBUF_WRITE(p1a, p1b);
    __syncthreads();
    if (!kw) PBUF_MERGE(p1a, p1b);
    __syncthreads();       // protect pbuf before h0's kw1 writes

    // ---- epilogue helper (kw0 only): v = acc + cv_i + fs*P1 -> relu ----
    #define H_EPILOGUE(IVEC, FS, WRITE_H)                                      \
    do {                                                                       \
        const float* cvi = cv + (IVEC)*448;                                    \
        const float* gvi = gv + (IVEC)*448;                                    \
        float vc0 = ok0 ? cvi[gn0] : 0.f;                                      \
        float vc1 = ok1 ? cvi[gn1] : 0.f;                                      \
        float wv0 = ok0 ? gvi[gn0] : 0.f;                                      \
        float wv1 = ok1 ? gvi[gn1] : 0.f;                                      \
        _Pragma("unroll")                                                      \
        for (int j = 0; j < 16; ++j) {                                         \
            int row = (j & 3) + 8*(j >> 2) + 4*hh;                             \
            float v0 = acc0[j] + vc0 + (FS)*p1a[j];                            \
            float v1 = acc1[j] + vc1 + (FS)*p1b[j];                            \
            v0 = fmaxf(v0, 0.f); v1 = fmaxf(v1, 0.f);                          \
            lrow[j] += v0*wv0 + v1*wv1;                                        \
            if (WRITE_H) {                                                     \
                unsigned short h16, l16;                                       \
                if (ok0) { split2(v0, h16, l16);                               \
                    hbuf[0][row][gn0] = h16; hbuf[1][row][gn0] = l16; }        \
                if (ok1) { split2(v1, h16, l16);                               \
                    hbuf[0][row][gn1] = h16; hbuf[1][row][gn1] = l16; }        \
            }                                                                  \
        }                                                                      \
    } while (0)

    // ---- stage h0: A = n0 (NK=13 -> 7/6), B = w0 (Kw=208) ----
    #pragma unroll
    for (int i = 0; i < 16; ++i) { acc0[i]=0.f; acc1[i]=0.f; }
    {
        const unsigned short* Ah  = n0h + ((size_t)mtile*13*64 + lane)*8 + kw*512;
        const unsigned short* Al  = n0l + ((size_t)mtile*13*64 + lane)*8 + kw*512;
        const unsigned short* B0h = w0 + ((size_t)(2*c)*64 + lane)*8 + (size_t)kw*8192;
        const unsigned short* B1h = w0 + ((size_t)(2*c+1)*64 + lane)*8 + (size_t)kw*8192;
        const unsigned short* B0l = B0h + (size_t)512*208;
        const unsigned short* B1l = B1h + (size_t)512*208;
        #pragma unroll
        for (int kq = 0; kq < 7; ++kq) {
            if (kq == 6 && kw) break;
            short8 ah  = *(const short8*)(Ah  + kq*1024);
            short8 al  = *(const short8*)(Al  + kq*1024);
            short8 b0h = *(const short8*)(B0h + kq*16384);
            short8 b1h = *(const short8*)(B1h + kq*16384);
            short8 b0l = *(const short8*)(B0l + kq*16384);
            short8 b1l = *(const short8*)(B1l + kq*16384);
            MFMA_STEP(ah, al, b0h, b1h, b0l, b1l, acc0, acc1)
        }
    }
    float fs0 = scal[2];
    if (kw) PBUF_WRITE(acc0, acc1);
    __syncthreads();
    if (!kw) { PBUF_MERGE(acc0, acc1); H_EPILOGUE(0, fs0, true); }
    __syncthreads();       // hbuf(h0) + pbuf free for next stage

    // ---- stages h1..h3: A = hbuf (NK=25 -> 13/12), B = w1/w2/w3 (Kw=400) ----
    #define H_STAGE_LDS(WPTR, IVEC, FS, WRITE_H, LAST)                         \
    do {                                                                       \
        _Pragma("unroll")                                                      \
        for (int i = 0; i < 16; ++i) { acc0[i]=0.f; acc1[i]=0.f; }             \
        const unsigned short* fAh = &hbuf[0][r31][hh*8] + kw*16;               \
        const unsigned short* fAl = &hbuf[1][r31][hh*8] + kw*16;               \
        const unsigned short* B0h = (WPTR) + ((size_t)(2*c)*64 + lane)*8 + (size_t)kw*8192;   \
        const unsigned short* B1h = (WPTR) + ((size_t)(2*c+1)*64 + lane)*8 + (size_t)kw*8192; \
        const unsigned short* B0l = B0h + (size_t)512*400;                     \
        const unsigned short* B1l = B1h + (size_t)512*400;                     \
        _Pragma("unroll")                                                      \
        for (int kq = 0; kq < 13; ++kq) {                                      \
            if (kq == 12 && kw) break;                                         \
            short8 ah  = *(const short8*)(fAh + kq*32);                        \
            short8 al  = *(const short8*)(fAl + kq*32);                        \
            short8 b0h = *(const short8*)(B0h + kq*16384);                     \
            short8 b1h = *(const short8*)(B1h + kq*16384);                     \
            short8 b0l = *(const short8*)(B0l + kq*16384);                     \
            short8 b1l = *(const short8*)(B1l + kq*16384);                     \
            MFMA_STEP(ah, al, b0h, b1h, b0l, b1l, acc0, acc1)                  \
        }                                                                      \
        if (kw) PBUF_WRITE(acc0, acc1);                                       \
        __syncthreads();                                                       \
        if (!kw) { PBUF_MERGE(acc0, acc1); H_EPILOGUE(IVEC, FS, WRITE_H); }    \
        if (!(LAST)) __syncthreads();                                          \
    } while (0)

    float fs1 = scal[8+2], fs2 = scal[16+2], fs3 = scal[24+2];
    H_STAGE_LDS(w1, 1, fs1, true,  false);
    H_STAGE_LDS(w2, 2, fs2, true,  false);
    H_STAGE_LDS(w3, 3, fs3, false, true);

    #undef H_STAGE_LDS
    #undef H_EPILOGUE
    #undef PBUF_WRITE
    #undef PBUF_MERGE

    // ---- final: one atomicAdd per row (kw0 waves only) ----
    if (!kw) {
        #pragma unroll
        for (int j = 0; j < 16; ++j) {
            float lv = lrow[j];
            #pragma unroll
            for (int o = 1; o < 32; o <<= 1) lv += __shfl_xor(lv, o);
            if (r31 == 0) {
                int row = (j & 3) + 8*(j >> 2) + 4*hh;
                atomicAdd(&out[bm + row], lv);
            }
        }
    }
}

// ---------------- host ----------------
static inline size_t align64(size_t x) { return (x + 63) & ~(size_t)63; }

extern "C" void kernel_launch(void* const* d_in, const int* in_sizes, int n_in,
                              void* d_out, int out_size, void* d_ws, size_t ws_size,
                              hipStream_t stream)
{
    const float* raw_dense  = (const float*)d_in[0];
    const int*   raw_sparse = (const int*)d_in[1];
    const float* emb   = (const float*)d_in[2];
    const float* Pd    = (const float*)d_in[3];
    const float* Ps    = (const float*)d_in[4];
    const float* Pb    = (const float*)d_in[5];
    const float* Wc    = (const float*)d_in[6];
    const float* bc    = (const float*)d_in[7];
    const float* clf_w = (const float*)d_in[8];
    const float* clf_b = (const float*)d_in[9];
    const float* a0 = (const float*)d_in[10];
    const float* a1 = (const float*)d_in[11];
    const float* a2 = (const float*)d_in[12];
    const float* a3 = (const float*)d_in[13];
    float* out = (float*)d_out;

    char* p = (char*)d_ws;
    auto alloc = [&](size_t bytes) { char* r = p; p += align64(bytes); return r; };

    float* scal    = (float*)alloc(32*4);
    float* partial = (float*)alloc(2*EMB_BLOCKS*4);
    float* csd     = (float*)alloc(400*4);
    float* css     = (float*)alloc(400*4);
    float* csb     = (float*)alloc(400*4);
    float* cv      = (float*)alloc(4*448*4);
    float* gv      = (float*)alloc(4*448*4);
    float* scl2    = (float*)alloc(16*4);
    unsigned short* w0 = (unsigned short*)alloc((size_t)2*512*208*2);
    unsigned short* w1 = (unsigned short*)alloc((size_t)2*512*400*2);
    unsigned short* w2 = (unsigned short*)alloc((size_t)2*512*400*2);
    unsigned short* w3 = (unsigned short*)alloc((size_t)2*512*400*2);
    unsigned short* ws = (unsigned short*)alloc((size_t)2*512*416*2);
    unsigned short* n0h = (unsigned short*)alloc((size_t)256*13*512*2);
    unsigned short* n0l = (unsigned short*)alloc((size_t)256*13*512*2);
    unsigned short* n1h = (unsigned short*)alloc((size_t)256*26*512*2);
    unsigned short* n1l = (unsigned short*)alloc((size_t)256*26*512*2);

    mega_prep<<<1151,256,0,stream>>>(raw_dense, raw_sparse, emb, Pd, Ps, Pb, Wc,
                                     a0,a1,a2,a3, scal, csd,css,csb,
                                     w0, ws, w1, w2, w3,
                                     n0h,n0l,n1h,n1l, partial);
    prepvec_kernel<<<dim3(14,4),256,0,stream>>>(scal,csd,css,csb,Wc,bc,clf_w,Pb,cv,gv,scl2);
    finalize_kernel<<<33,256,0,stream>>>(clf_b, partial, scl2, out);

    // whole chain: P1 + h0..h3 + fused logits, one dispatch
    fused_chain<<<256,896,0,stream>>>(n0h,n0l,n1h,n1l, ws,w0,w1,w2,w3,
                                      scal, cv, gv, out);
}

// Round 13
// 262.505 us; speedup vs baseline: 1.5848x; 1.0036x over previous
//
#include <hip/hip_runtime.h>
#include <cstddef>

// DynamicNetwork via split-bf16 MFMA (hi/lo, 3 MFMA per product).
// R8: algebraic fusion — nodes 2..5 never materialized.
// R15: P1 = node1@Ps computed once; h-GEMMs K 816->400.
// R17: whole-chain fusion (P1+h0..h3+logits, one dispatch).
// R18: fragment-order repack (coalesced 1KB wave loads).
// R19: 14-wave k-split fused chain + mega-prep — 263us, fused=64us.
// R20: (a) pbuf transposed [14][16][64] (lane-fastest): R19's [.][64][16] put
//   64 lanes on 2 banks (~32-way conflict, 2.58M cycles) on every partial
//   write/merge; lane-contiguous scalar ops are conflict-free.
//   (b) s_setprio(1) around MFMA loops (T5): kw0/kw1 role diversity gives the
//   scheduler something to arbitrate.
// R21: identical resubmit of R20 — R12 bench failed on container acquisition
//   (infra, same signature as R4); audit found no defect in the R19->R20 delta.

typedef short short8 __attribute__((ext_vector_type(8)));
typedef float floatx16 __attribute__((ext_vector_type(16)));

#define EMB_BLOCKS 832

__device__ __forceinline__ unsigned short f2bf(float f) {
    unsigned int u = __float_as_uint(f);
    u += 0x7fffu + ((u >> 16) & 1u);
    return (unsigned short)(u >> 16);
}
__device__ __forceinline__ float bf2f(unsigned short h) {
    return __uint_as_float((unsigned int)h << 16);
}
__device__ __forceinline__ void split2(float v, unsigned short& h, unsigned short& l) {
    h = f2bf(v);
    l = f2bf(v - bf2f(h));
}

// ---------------- mega_prep: embed(832) + prep1(39) + prep2(112) + prepM(168) ----------------
__global__ __launch_bounds__(256) void mega_prep(
    const float* __restrict__ rd, const int* __restrict__ rs,
    const float* __restrict__ emb,
    const float* __restrict__ Pd, const float* __restrict__ Ps, const float* __restrict__ Pb,
    const float* __restrict__ Wc,
    const float* __restrict__ a0, const float* __restrict__ a1,
    const float* __restrict__ a2, const float* __restrict__ a3,
    float* __restrict__ scal,
    float* __restrict__ csd, float* __restrict__ css, float* __restrict__ csb,
    unsigned short* __restrict__ w0, unsigned short* __restrict__ ws,
    unsigned short* __restrict__ w1, unsigned short* __restrict__ w2,
    unsigned short* __restrict__ w3,
    unsigned short* __restrict__ n0h, unsigned short* __restrict__ n0l,
    unsigned short* __restrict__ n1h, unsigned short* __restrict__ n1l,
    float* __restrict__ partial)
{
    __shared__ __align__(16) float smem[64*65];   // 16640B, unioned across roles
    int bid = blockIdx.x;
    int t = threadIdx.x;

    if (bid < 832) {
        // ---------------- embed role (fragment-packed outputs) ----------------
        int tid0 = bid*256 + t;
        const int nth = 832*256;
        float ssq = 0.f, dsq = 0.f;
        for (int it = tid0; it < 8192*26; it += nth) {
            int s = it >> 13, b = it & 8191;
            int row = 13 + 50000*s + rs[b*26 + s];
            const float* e = emb + (size_t)row*16;
            float4 e0 = *(const float4*)&e[0], e1 = *(const float4*)&e[4];
            float4 e2 = *(const float4*)&e[8], e3 = *(const float4*)&e[12];
            float vv[16] = {e0.x,e0.y,e0.z,e0.w, e1.x,e1.y,e1.z,e1.w,
                            e2.x,e2.y,e2.z,e2.w, e3.x,e3.y,e3.z,e3.w};
            unsigned short hb[16], lb[16];
            for (int j = 0; j < 16; ++j) { ssq += vv[j]*vv[j]; split2(vv[j], hb[j], lb[j]); }
            size_t off = (((size_t)(b>>5)*26 + s)*64 + (b&31))*8;
            *(uint4*)&n1h[off]       = *(uint4*)&hb[0];
            *(uint4*)&n1h[off + 256] = *(uint4*)&hb[8];
            *(uint4*)&n1l[off]       = *(uint4*)&lb[0];
            *(uint4*)&n1l[off + 256] = *(uint4*)&lb[8];
        }
        for (int it = tid0; it < 8192*13; it += nth) {
            int f = it >> 13, b = it & 8191;
            float sc = rd[b*13 + f];
            const float* e = emb + (size_t)f*16;
            float4 e0 = *(const float4*)&e[0], e1 = *(const float4*)&e[4];
            float4 e2 = *(const float4*)&e[8], e3 = *(const float4*)&e[12];
            float vv[16] = {e0.x,e0.y,e0.z,e0.w, e1.x,e1.y,e1.z,e1.w,
                            e2.x,e2.y,e2.z,e2.w, e3.x,e3.y,e3.z,e3.w};
            unsigned short hb[16], lb[16];
            for (int j = 0; j < 16; ++j) { float v = vv[j]*sc; dsq += v*v; split2(v, hb[j], lb[j]); }
            size_t off = (((size_t)(b>>5)*13 + f)*64 + (b&31))*8;
            *(uint4*)&n0h[off]       = *(uint4*)&hb[0];
            *(uint4*)&n0h[off + 256] = *(uint4*)&hb[8];
            *(uint4*)&n0l[off]       = *(uint4*)&lb[0];
            *(uint4*)&n0l[off + 256] = *(uint4*)&lb[8];
        }
        for (int o = 32; o > 0; o >>= 1) { ssq += __shfl_down(ssq, o); dsq += __shfl_down(dsq, o); }
        float* red = smem;
        int wave = t >> 6, lane = t & 63;
        if (lane == 0) { red[wave] = dsq; red[4+wave] = ssq; }
        __syncthreads();
        if (t == 0) {
            partial[bid*2]   = red[0]+red[1]+red[2]+red[3];
            partial[bid*2+1] = red[4]+red[5]+red[6]+red[7];
        }
        return;
    }
    if (bid < 871) {
        // ---------------- prep1 role: column sums + alpha scalars ----------------
        int r = bid - 832;
        int x = r % 13, y = r / 13;
        int c = t & 31, rg = t >> 5;
        int col = x * 32 + c;
        const float* src = (y==0) ? Pd : (y==1) ? Ps : Pb;
        int K = (y==0) ? 208 : (y==1) ? 416 : 400;
        float* outp = (y==0) ? csd : (y==1) ? css : csb;
        float s = 0.f;
        if (col < 400)
            for (int k = rg; k < K; k += 8) s += src[(size_t)k*400 + col];
        float (*red)[32] = (float(*)[32])smem;
        red[rg][c] = s;
        __syncthreads();
        if (rg == 0 && col < 400) {
            float tot = 0.f;
            #pragma unroll
            for (int rr = 0; rr < 8; ++rr) tot += red[rr][c];
            outp[col] = tot;
        }
        if (x == 0 && y == 0 && t < 4) {
            int i = t;
            const float* a = (i==0) ? a0 : (i==1) ? a1 : (i==2) ? a2 : a3;
            int np = 2 + i;
            float sum1 = 0.f, sum2 = 0.f, sumc = 0.f;
            for (int j = 0; j < np; ++j) { sum1 += a[j]; sum2 += a[np+j]; }
            for (int j = 0; j < 4; ++j) sumc += a[2*np+j];
            int i1 = (i==0) ? 0 : 1;
            int i2 = i + 1;
            int kk = i;
            float s1 = a[i1],      c1 = sum1 - s1;
            float s2 = a[np+i2],   c2 = sum2 - s2;
            float sk = a[2*np+kk], ck = sumc - sk;
            float* sl = scal + i*8;
            if (i == 0) { sl[0]=s1; sl[1]=c1; sl[2]=s2; sl[3]=c2; }
            else        { sl[0]=s2; sl[1]=c2; sl[2]=s1; sl[3]=c1; }
            sl[4] = sk; sl[5] = ck;
        }
        return;
    }
    if (bid < 983) {
        // ---------------- prep2 role: w0 = s1*Pd (K=208); ws = Ps (K=416) ----------------
        int r = bid - 871;
        int z = r / 56, rem = r % 56;
        int y = rem / 8, x = rem % 8;
        int Kp = (z==0) ? 208 : 416;
        const float* src = (z==0) ? Pd : Ps;
        unsigned short* dst = (z==0) ? w0 : ws;
        size_t plo = (size_t)512 * Kp;
        int ktiles = (Kp + 63) >> 6;
        if (y >= ktiles) return;
        float sc = (z==0) ? a0[0] : 1.f;       // s1 for i=0 is a0[i1=0]
        int k0 = y * 64, n0 = x * 64;
        float (*T)[65] = (float(*)[65])smem;
        {
            int kr = t >> 2, c0 = (t & 3) * 16;
            int gk = k0 + kr;
            bool kok = gk < Kp;
            for (int j = 0; j < 16; j += 4) {
                int n = n0 + c0 + j;
                float4 v = make_float4(0.f,0.f,0.f,0.f);
                if (kok && n < 400) v = *(const float4*)&src[(size_t)gk*400 + n];
                T[kr][c0+j+0] = v.x * sc;
                T[kr][c0+j+1] = v.y * sc;
                T[kr][c0+j+2] = v.z * sc;
                T[kr][c0+j+3] = v.w * sc;
            }
        }
        __syncthreads();
        {
            int nr = t >> 2, kc0 = (t & 3) * 16;
            int gn = n0 + nr;
            int gk0 = k0 + kc0;
            if (gk0 >= Kp) return;
            unsigned short hb[16], lb[16];
            for (int j = 0; j < 16; ++j) {
                float v = (gn < 400) ? T[kc0+j][nr] : 0.f;
                split2(v, hb[j], lb[j]);
            }
            int kb = gk0 >> 4;
            size_t off = (((size_t)kb*16 + (gn>>5))*64 + (gn&31))*8;
            *(uint4*)&dst[off]             = *(uint4*)&hb[0];
            *(uint4*)&dst[off + 256]       = *(uint4*)&hb[8];
            *(uint4*)&dst[plo + off]       = *(uint4*)&lb[0];
            *(uint4*)&dst[plo + off + 256] = *(uint4*)&lb[8];
        }
        return;
    }
    {
        // ---------------- prepM role: M_g fragment-packed ----------------
        int r = bid - 983;
        int z = r / 56, rem = r % 56;
        int by = rem / 8, bx = rem % 8;
        unsigned short* dst = (z==0) ? w1 : (z==1) ? w2 : w3;
        const float* A = Wc + (size_t)z*5*160000;
        // scale = s2_{z+1} * sk_z = a_{z+1}[2z+5] * a_z[3z+4]
        const float* az1 = (z==0) ? a1 : (z==1) ? a2 : a3;
        const float* az  = (z==0) ? a0 : (z==1) ? a1 : a2;
        float scale = az1[2*z+5] * az[3*z+4];
        const size_t plo = (size_t)512*400;

        float (*As)[68] = (float(*)[68])smem;          // 16 rows
        float (*Ws)[68] = (float(*)[68])(smem + 16*68); // 16 rows
        int tx = t & 15, ty = t >> 4;
        int bk = by * 64;
        int bn = bx * 64;
        int arow = t >> 2;
        int aj4  = (t & 3) << 2;
        int wrow = t >> 4;
        int wc4  = (t & 15) << 2;
        float acc[4][4] = {};
        for (int j0 = 0; j0 < 400; j0 += 16) {
            float4 av = make_float4(0.f,0.f,0.f,0.f);
            if (bk + arow < 400) av = *(const float4*)&A[(size_t)(bk+arow)*400 + j0 + aj4];
            float4 wv = make_float4(0.f,0.f,0.f,0.f);
            if (bn + wc4 < 400) wv = *(const float4*)&Pb[(size_t)(j0+wrow)*400 + bn + wc4];
            __syncthreads();
            As[aj4+0][arow] = av.x;
            As[aj4+1][arow] = av.y;
            As[aj4+2][arow] = av.z;
            As[aj4+3][arow] = av.w;
            *(float4*)&Ws[wrow][wc4] = wv;
            __syncthreads();
            #pragma unroll
            for (int jj = 0; jj < 16; ++jj) {
                float4 a4 = *(const float4*)&As[jj][ty<<2];
                float4 b4 = *(const float4*)&Ws[jj][tx<<2];
                acc[0][0] += a4.x*b4.x; acc[0][1] += a4.x*b4.y; acc[0][2] += a4.x*b4.z; acc[0][3] += a4.x*b4.w;
                acc[1][0] += a4.y*b4.x; acc[1][1] += a4.y*b4.y; acc[1][2] += a4.y*b4.z; acc[1][3] += a4.y*b4.w;
                acc[2][0] += a4.z*b4.x; acc[2][1] += a4.z*b4.y; acc[2][2] += a4.z*b4.z; acc[2][3] += a4.z*b4.w;
                acc[3][0] += a4.w*b4.x; acc[3][1] += a4.w*b4.y; acc[3][2] += a4.w*b4.z; acc[3][3] += a4.w*b4.w;
            }
        }
        int gk0 = bk + (ty << 2);
        int gn0 = bn + (tx << 2);
        #pragma unroll
        for (int ik = 0; ik < 4; ++ik) {
            int gk = gk0 + ik;
            if (gk >= 400) break;
            int kb = gk >> 4, hh8 = (gk >> 3) & 1, e = gk & 7;
            #pragma unroll
            for (int in = 0; in < 4; ++in) {
                int gn = gn0 + in;
                float v = (gn < 400) ? acc[ik][in] * scale : 0.f;
                unsigned short h16, l16; split2(v, h16, l16);
                size_t off = (((size_t)kb*16 + (gn>>5))*64 + hh8*32 + (gn&31))*8 + e;
                dst[off] = h16;
                dst[plo + off] = l16;
            }
        }
    }
}

// ---------------- prepvec: C_i, gv_i, scalar consts (56 blocks) ----------------
__global__ __launch_bounds__(256) void prepvec_kernel(
    const float* __restrict__ scal,
    const float* __restrict__ csd, const float* __restrict__ css, const float* __restrict__ csb,
    const float* __restrict__ Wc, const float* __restrict__ bc,
    const float* __restrict__ clf_w, const float* __restrict__ Pb,
    float* __restrict__ cv, float* __restrict__ gv, float* __restrict__ scl2)
{
    int i = blockIdx.y;
    int tid = threadIdx.x;
    int tbase = blockIdx.x * 32;
    const float* cw = clf_w + i*400;
    float ski = scal[i*8+4], cki = scal[i*8+5];
    const float* A = Wc + (size_t)i*5*160000;

    int wv = tid >> 6, lane = tid & 63;
    #pragma unroll
    for (int q = 0; q < 8; ++q) {
        int t = tbase + wv*8 + q;
        float s = 0.f;
        if (t < 400) {
            const float* wr = A + (size_t)t*400;
            for (int j = lane; j < 400; j += 64) s += wr[j]*cw[j];
            #pragma unroll
            for (int o = 32; o > 0; o >>= 1) s += __shfl_xor(s, o);
        }
        if (lane == 0) gv[i*448 + t] = (t < 400) ? ski * s : 0.f;
    }

    __shared__ float bpred[8][32];
    int t = tbase + (tid & 31);
    int jc = tid >> 5;
    float bp_part = 0.f;
    if (i > 0 && t < 400) {
        const float* bcp = bc + (size_t)(i-1)*5*400;
        for (int j = jc*50; j < jc*50 + 50; ++j)
            bp_part += bcp[j] * Pb[(size_t)j*400 + t];
    }
    bpred[jc][tid & 31] = bp_part;
    __syncthreads();
    if (tid < 32) {
        float bp = 0.f;
        #pragma unroll
        for (int r = 0; r < 8; ++r) bp += bpred[r][tid];
        float c = 0.f;
        if (t < 400) {
            if (i == 0) {
                c = scal[1]*csd[t] + scal[3]*css[t];
            } else {
                float s2 = scal[i*8+0], c2 = scal[i*8+1];
                float c1 = scal[i*8+3];
                float skp = scal[(i-1)*8+4], ckp = scal[(i-1)*8+5];
                c = c1*css[t] + (c2 + s2*ckp)*csb[t] + s2*skp*bp;
            }
        }
        cv[i*448 + t] = c;
    }

    if (blockIdx.x == 0) {
        const float* bci = bc + (size_t)i*5*400;
        float sc = 0.f;
        for (int j = tid; j < 400; j += 256) sc += (ski*bci[j] + cki)*cw[j];
        #pragma unroll
        for (int o = 32; o > 0; o >>= 1) sc += __shfl_down(sc, o);
        __shared__ float red[4];
        int wv2 = tid >> 6, ln = tid & 63;
        if (ln == 0) red[wv2] = sc;
        __syncthreads();
        if (tid == 0) scl2[i] = red[0]+red[1]+red[2]+red[3];
    }
}

// blocks 0..31: out[b] = clf_b + sum_i scl2[i]; block 32: regs
__global__ __launch_bounds__(256) void finalize_kernel(
    const float* __restrict__ clf_b, const float* __restrict__ partial,
    const float* __restrict__ scl2, float* __restrict__ out)
{
    if (blockIdx.x < 32) {
        float base = clf_b[0] + scl2[0] + scl2[1] + scl2[2] + scl2[3];
        out[blockIdx.x*256 + threadIdx.x] = base;
        return;
    }
    float d = 0.f, s = 0.f;
    for (int i = threadIdx.x; i < EMB_BLOCKS; i += 256) { d += partial[2*i]; s += partial[2*i+1]; }
    for (int o = 32; o > 0; o >>= 1) { d += __shfl_down(d, o); s += __shfl_down(s, o); }
    __shared__ float red[8];
    int wave = threadIdx.x >> 6, lane = threadIdx.x & 63;
    if (lane == 0) { red[wave] = d; red[4+wave] = s; }
    __syncthreads();
    if (threadIdx.x == 0) {
        float dd = red[0]+red[1]+red[2]+red[3];
        float ss = red[4]+red[5]+red[6]+red[7];
        out[8192] = 1e-5f * (sqrtf(dd) + sqrtf(ss));
    }
}

// ---------------- R20 fused chain: 14 waves, k-split pairs, clean pbuf ----------------
// Grid 256 x 896 (14 waves). Wave = (c = W%7 col-tile, kw = W/7 k-half).
// pbuf transposed [slot][j][lane]: partial write/merge is lane-contiguous
// scalar f32 -> conflict-free. s_setprio(1) around MFMA loops (T5).
#define MFMA_STEP(AH, AL, B0H, B1H, B0L, B1L, ACC0, ACC1)                      \
    ACC0 = __builtin_amdgcn_mfma_f32_32x32x16_bf16(AH, B0H, ACC0,0,0,0);       \
    ACC1 = __builtin_amdgcn_mfma_f32_32x32x16_bf16(AH, B1H, ACC1,0,0,0);       \
    ACC0 = __builtin_amdgcn_mfma_f32_32x32x16_bf16(AH, B0L, ACC0,0,0,0);       \
    ACC1 = __builtin_amdgcn_mfma_f32_32x32x16_bf16(AH, B1L, ACC1,0,0,0);       \
    ACC0 = __builtin_amdgcn_mfma_f32_32x32x16_bf16(AL, B0H, ACC0,0,0,0);       \
    ACC1 = __builtin_amdgcn_mfma_f32_32x32x16_bf16(AL, B1H, ACC1,0,0,0);

__global__ __launch_bounds__(896, 4) void fused_chain(
    const unsigned short* __restrict__ n0h, const unsigned short* __restrict__ n0l,
    const unsigned short* __restrict__ n1h, const unsigned short* __restrict__ n1l,
    const unsigned short* __restrict__ ws,
    const unsigned short* __restrict__ w0,
    const unsigned short* __restrict__ w1,
    const unsigned short* __restrict__ w2,
    const unsigned short* __restrict__ w3,
    const float* __restrict__ scal,
    const float* __restrict__ cv, const float* __restrict__ gv,
    float* __restrict__ out)
{
    __shared__ __align__(16) unsigned short hbuf[2][32][408];   // 52224 B
    __shared__ __align__(16) float pbuf[14][16][64];            // 57344 B

    int tid = threadIdx.x;
    int W = tid >> 6, lane = tid & 63;
    int r31 = lane & 31, hh = lane >> 5;
    int c = W % 7, kw = W / 7;
    int mtile = blockIdx.x;
    int bm = mtile * 32;

    int gn0 = c*64 + r31;
    int gn1 = gn0 + 32;
    bool ok0 = gn0 < 400, ok1 = gn1 < 400;

    floatx16 p1a, p1b, acc0, acc1;
    float lrow[16];
    #pragma unroll
    for (int i = 0; i < 16; ++i) { p1a[i]=0.f; p1b[i]=0.f; lrow[i]=0.f; }

    #define PBUF_WRITE(V0, V1)                                                 \
    do {                                                                       \
        _Pragma("unroll")                                                      \
        for (int j = 0; j < 16; ++j) {                                         \
            pbuf[2*c  ][j][lane] = V0[j];                                      \
            pbuf[2*c+1][j][lane] = V1[j];                                      \
        }                                                                      \
    } while (0)

    #define PBUF_MERGE(V0, V1)                                                 \
    do {                                                                       \
        _Pragma("unroll")                                                      \
        for (int j = 0; j < 16; ++j) {                                         \
            V0[j] += pbuf[2*c][j][lane];                                       \
            V1[j] += pbuf[2*c+1][j][lane];                                     \
        }                                                                      \
    } while (0)

    // ---- stage P1: A = n1 (NK=26 -> 13/13), B = ws (Kw=416) ----
    {
        const unsigned short* Ah  = n1h + ((size_t)mtile*26*64 + lane)*8 + kw*512;
        const unsigned short* Al  = n1l + ((size_t)mtile*26*64 + lane)*8 + kw*512;
        const unsigned short* B0h = ws + ((size_t)(2*c)*64 + lane)*8 + (size_t)kw*8192;
        const unsigned short* B1h = ws + ((size_t)(2*c+1)*64 + lane)*8 + (size_t)kw*8192;
        const unsigned short* B0l = B0h + (size_t)512*416;
        const unsigned short* B1l = B1h + (size_t)512*416;
        __builtin_amdgcn_s_setprio(1);
        #pragma unroll
        for (int kq = 0; kq < 13; ++kq) {
            short8 ah  = *(const short8*)(Ah  + kq*1024);
            short8 al  = *(const short8*)(Al  + kq*1024);
            short8 b0h = *(const short8*)(B0h + kq*16384);
            short8 b1h = *(const short8*)(B1h + kq*16384);
            short8 b0l = *(const short8*)(B0l + kq*16384);
            short8 b1l = *(const short8*)(B1l + kq*16384);
            MFMA_STEP(ah, al, b0h, b1h, b0l, b1l, p1a, p1b)
        }
        __builtin_amdgcn_s_setprio(0);
    }
    if (kw) PBUF_WRITE(p1a, p1b);
    __syncthreads();
    if (!kw) PBUF_MERGE(p1a, p1b);
    __syncthreads();       // protect pbuf before h0's kw1 writes

    // ---- epilogue helper (kw0 only): v = acc + cv_i + fs*P1 -> relu ----
    #define H_EPILOGUE(IVEC, FS, WRITE_H)                                      \
    do {                                                                       \
        const float* cvi = cv + (IVEC)*448;                                    \
        const float* gvi = gv + (IVEC)*448;                                    \
        float vc0 = ok0 ? cvi[gn0] : 0.f;                                      \
        float vc1 = ok1 ? cvi[gn1] : 0.f;                                      \
        float wv0 = ok0 ? gvi[gn0] : 0.f;                                      \
        float wv1 = ok1 ? gvi[gn1] : 0.f;                                      \
        _Pragma("unroll")                                                      \
        for (int j = 0; j < 16; ++j) {                                         \
            int row = (j & 3) + 8*(j >> 2) + 4*hh;                             \
            float v0 = acc0[j] + vc0 + (FS)*p1a[j];                            \
            float v1 = acc1[j] + vc1 + (FS)*p1b[j];                            \
            v0 = fmaxf(v0, 0.f); v1 = fmaxf(v1, 0.f);                          \
            lrow[j] += v0*wv0 + v1*wv1;                                        \
            if (WRITE_H) {                                                     \
                unsigned short h16, l16;                                       \
                if (ok0) { split2(v0, h16, l16);                               \
                    hbuf[0][row][gn0] = h16; hbuf[1][row][gn0] = l16; }        \
                if (ok1) { split2(v1, h16, l16);                               \
                    hbuf[0][row][gn1] = h16; hbuf[1][row][gn1] = l16; }        \
            }                                                                  \
        }                                                                      \
    } while (0)

    // ---- stage h0: A = n0 (NK=13 -> 7/6), B = w0 (Kw=208) ----
    #pragma unroll
    for (int i = 0; i < 16; ++i) { acc0[i]=0.f; acc1[i]=0.f; }
    {
        const unsigned short* Ah  = n0h + ((size_t)mtile*13*64 + lane)*8 + kw*512;
        const unsigned short* Al  = n0l + ((size_t)mtile*13*64 + lane)*8 + kw*512;
        const unsigned short* B0h = w0 + ((size_t)(2*c)*64 + lane)*8 + (size_t)kw*8192;
        const unsigned short* B1h = w0 + ((size_t)(2*c+1)*64 + lane)*8 + (size_t)kw*8192;
        const unsigned short* B0l = B0h + (size_t)512*208;
        const unsigned short* B1l = B1h + (size_t)512*208;
        __builtin_amdgcn_s_setprio(1);
        #pragma unroll
        for (int kq = 0; kq < 7; ++kq) {
            if (kq == 6 && kw) break;
            short8 ah  = *(const short8*)(Ah  + kq*1024);
            short8 al  = *(const short8*)(Al  + kq*1024);
            short8 b0h = *(const short8*)(B0h + kq*16384);
            short8 b1h = *(const short8*)(B1h + kq*16384);
            short8 b0l = *(const short8*)(B0l + kq*16384);
            short8 b1l = *(const short8*)(B1l + kq*16384);
            MFMA_STEP(ah, al, b0h, b1h, b0l, b1l, acc0, acc1)
        }
        __builtin_amdgcn_s_setprio(0);
    }
    float fs0 = scal[2];
    if (kw) PBUF_WRITE(acc0, acc1);
    __syncthreads();
    if (!kw) { PBUF_MERGE(acc0, acc1); H_EPILOGUE(0, fs0, true); }
    __syncthreads();       // hbuf(h0) + pbuf free for next stage

    // ---- stages h1..h3: A = hbuf (NK=25 -> 13/12), B = w1/w2/w3 (Kw=400) ----
    #define H_STAGE_LDS(WPTR, IVEC, FS, WRITE_H, LAST)                         \
    do {                                                                       \
        _Pragma("unroll")                                                      \
        for (int i = 0; i < 16; ++i) { acc0[i]=0.f; acc1[i]=0.f; }             \
        const unsigned short* fAh = &hbuf[0][r31][hh*8] + kw*16;               \
        const unsigned short* fAl = &hbuf[1][r31][hh*8] + kw*16;               \
        const unsigned short* B0h = (WPTR) + ((size_t)(2*c)*64 + lane)*8 + (size_t)kw*8192;   \
        const unsigned short* B1h = (WPTR) + ((size_t)(2*c+1)*64 + lane)*8 + (size_t)kw*8192; \
        const unsigned short* B0l = B0h + (size_t)512*400;                     \
        const unsigned short* B1l = B1h + (size_t)512*400;                     \
        __builtin_amdgcn_s_setprio(1);                                         \
        _Pragma("unroll")                                                      \
        for (int kq = 0; kq < 13; ++kq) {                                      \
            if (kq == 12 && kw) break;                                         \
            short8 ah  = *(const short8*)(fAh + kq*32);                        \
            short8 al  = *(const short8*)(fAl + kq*32);                        \
            short8 b0h = *(const short8*)(B0h + kq*16384);                     \
            short8 b1h = *(const short8*)(B1h + kq*16384);                     \
            short8 b0l = *(const short8*)(B0l + kq*16384);                     \
            short8 b1l = *(const short8*)(B1l + kq*16384);                     \
            MFMA_STEP(ah, al, b0h, b1h, b0l, b1l, acc0, acc1)                  \
        }                                                                      \
        __builtin_amdgcn_s_setprio(0);                                         \
        if (kw) PBUF_WRITE(acc0, acc1);                                       \
        __syncthreads();                                                       \
        if (!kw) { PBUF_MERGE(acc0, acc1); H_EPILOGUE(IVEC, FS, WRITE_H); }    \
        if (!(LAST)) __syncthreads();                                          \
    } while (0)

    float fs1 = scal[8+2], fs2 = scal[16+2], fs3 = scal[24+2];
    H_STAGE_LDS(w1, 1, fs1, true,  false);
    H_STAGE_LDS(w2, 2, fs2, true,  false);
    H_STAGE_LDS(w3, 3, fs3, false, true);

    #undef H_STAGE_LDS
    #undef H_EPILOGUE
    #undef PBUF_WRITE
    #undef PBUF_MERGE

    // ---- final: one atomicAdd per row (kw0 waves only) ----
    if (!kw) {
        #pragma unroll
        for (int j = 0; j < 16; ++j) {
            float lv = lrow[j];
            #pragma unroll
            for (int o = 1; o < 32; o <<= 1) lv += __shfl_xor(lv, o);
            if (r31 == 0) {
                int row = (j & 3) + 8*(j >> 2) + 4*hh;
                atomicAdd(&out[bm + row], lv);
            }
        }
    }
}

// ---------------- host ----------------
static inline size_t align64(size_t x) { return (x + 63) & ~(size_t)63; }

extern "C" void kernel_launch(void* const* d_in, const int* in_sizes, int n_in,
                              void* d_out, int out_size, void* d_ws, size_t ws_size,
                              hipStream_t stream)
{
    const float* raw_dense  = (const float*)d_in[0];
    const int*   raw_sparse = (const int*)d_in[1];
    const float* emb   = (const float*)d_in[2];
    const float* Pd    = (const float*)d_in[3];
    const float* Ps    = (const float*)d_in[4];
    const float* Pb    = (const float*)d_in[5];
    const float* Wc    = (const float*)d_in[6];
    const float* bc    = (const float*)d_in[7];
    const float* clf_w = (const float*)d_in[8];
    const float* clf_b = (const float*)d_in[9];
    const float* a0 = (const float*)d_in[10];
    const float* a1 = (const float*)d_in[11];
    const float* a2 = (const float*)d_in[12];
    const float* a3 = (const float*)d_in[13];
    float* out = (float*)d_out;

    char* p = (char*)d_ws;
    auto alloc = [&](size_t bytes) { char* r = p; p += align64(bytes); return r; };

    float* scal    = (float*)alloc(32*4);
    float* partial = (float*)alloc(2*EMB_BLOCKS*4);
    float* csd     = (float*)alloc(400*4);
    float* css     = (float*)alloc(400*4);
    float* csb     = (float*)alloc(400*4);
    float* cv      = (float*)alloc(4*448*4);
    float* gv      = (float*)alloc(4*448*4);
    float* scl2    = (float*)alloc(16*4);
    unsigned short* w0 = (unsigned short*)alloc((size_t)2*512*208*2);
    unsigned short* w1 = (unsigned short*)alloc((size_t)2*512*400*2);
    unsigned short* w2 = (unsigned short*)alloc((size_t)2*512*400*2);
    unsigned short* w3 = (unsigned short*)alloc((size_t)2*512*400*2);
    unsigned short* ws = (unsigned short*)alloc((size_t)2*512*416*2);
    unsigned short* n0h = (unsigned short*)alloc((size_t)256*13*512*2);
    unsigned short* n0l = (unsigned short*)alloc((size_t)256*13*512*2);
    unsigned short* n1h = (unsigned short*)alloc((size_t)256*26*512*2);
    unsigned short* n1l = (unsigned short*)alloc((size_t)256*26*512*2);

    mega_prep<<<1151,256,0,stream>>>(raw_dense, raw_sparse, emb, Pd, Ps, Pb, Wc,
                                     a0,a1,a2,a3, scal, csd,css,csb,
                                     w0, ws, w1, w2, w3,
                                     n0h,n0l,n1h,n1l, partial);
    prepvec_kernel<<<dim3(14,4),256,0,stream>>>(scal,csd,css,csb,Wc,bc,clf_w,Pb,cv,gv,scl2);
    finalize_kernel<<<33,256,0,stream>>>(clf_b, partial, scl2, out);

    // whole chain: P1 + h0..h3 + fused logits, one dispatch
    fused_chain<<<256,896,0,stream>>>(n0h,n0l,n1h,n1l, ws,w0,w1,w2,w3,
                                      scal, cv, gv, out);
}